// Round 2
// baseline (1468.288 us; speedup 1.0000x reference)
//
#include <hip/hip_runtime.h>

typedef unsigned short u16;
typedef unsigned int u32;
typedef __attribute__((ext_vector_type(8))) __bf16 bf16x8;
typedef __attribute__((ext_vector_type(4))) float f32x4;

#define B_ 8
#define S_ 1024
#define D_ 1024
#define H_ 16
#define DK_ 64
#define DFF_ 4096

__device__ __forceinline__ float bflo(u32 u) { return __uint_as_float(u << 16); }
__device__ __forceinline__ float bfhi(u32 u) { return __uint_as_float(u & 0xffff0000u); }
__device__ __forceinline__ u16 f2bf(float f) {
    u32 u = __float_as_uint(f);
    u += 0x7fffu + ((u >> 16) & 1u);   // RNE
    return (u16)(u >> 16);
}

// ---------------------------------------------------------------------------
// Dtype sniffer: true-bf16 weights (wq ~ N(0,1)/32) give |v| <= ~0.3 for every
// u16; fp32 data read as bf16 has mantissa-half u16s with random exponents ->
// max |v| >> 1e3 with probability ~1. One block, writes flag (1 = fp32).
// ---------------------------------------------------------------------------
__global__ __launch_bounds__(256) void sniff_kernel(const u16* __restrict__ w,
                                                    int* __restrict__ flag) {
    float mx = 0.f;
    for (int i = threadIdx.x; i < 4096; i += 256) {
        float v = fabsf(bflo((u32)w[i]));
        if (!isnan(v)) mx = fmaxf(mx, v);
    }
#pragma unroll
    for (int m = 1; m < 64; m <<= 1) mx = fmaxf(mx, __shfl_xor(mx, m, 64));
    __shared__ float wmx[4];
    if ((threadIdx.x & 63) == 0) wmx[threadIdx.x >> 6] = mx;
    __syncthreads();
    if (threadIdx.x == 0) {
        float m2 = fmaxf(fmaxf(wmx[0], wmx[1]), fmaxf(wmx[2], wmx[3]));
        *flag = (m2 > 1e3f) ? 1 : 0;
    }
}

// Normalize any float input into canonical bf16 (convert fp32 or copy bf16).
__global__ __launch_bounds__(256) void norm_kernel(const void* __restrict__ in,
                                                   u16* __restrict__ out, int n,
                                                   const int* __restrict__ flag) {
    const int i = blockIdx.x * 256 + threadIdx.x;
    if (i >= n) return;
    if (*flag)
        out[i] = f2bf(((const float*)in)[i]);
    else
        out[i] = ((const u16*)in)[i];
}

// ---------------------------------------------------------------------------
// LayerNorm (ddof=1, scalar gamma/beta). One block per row of 1024.
// INF32: 0 = bf16 input, 1 = fp32 input. Output bf16.
// ---------------------------------------------------------------------------
template <int INF32>
__global__ __launch_bounds__(256) void ln_kernel(const void* __restrict__ in,
                                                 const u16* __restrict__ gs,
                                                 const u16* __restrict__ bs,
                                                 u16* __restrict__ out) {
    const int row = blockIdx.x, t = threadIdx.x;
    float v0, v1, v2, v3;
    if (INF32) {
        const float* p = (const float*)in + (size_t)row * D_ + t * 4;
        float4 f = *(const float4*)p;
        v0 = f.x; v1 = f.y; v2 = f.z; v3 = f.w;
    } else {
        const u16* p = (const u16*)in + (size_t)row * D_ + t * 4;
        uint2 u = *(const uint2*)p;
        v0 = bflo(u.x); v1 = bfhi(u.x); v2 = bflo(u.y); v3 = bfhi(u.y);
    }
    float s = v0 + v1 + v2 + v3;
    float sq = v0 * v0 + v1 * v1 + v2 * v2 + v3 * v3;
#pragma unroll
    for (int m = 1; m < 64; m <<= 1) {
        s += __shfl_xor(s, m, 64);
        sq += __shfl_xor(sq, m, 64);
    }
    __shared__ float ss[4], sqs[4];
    const int w = t >> 6;
    if ((t & 63) == 0) { ss[w] = s; sqs[w] = sq; }
    __syncthreads();
    s = ss[0] + ss[1] + ss[2] + ss[3];
    sq = sqs[0] + sqs[1] + sqs[2] + sqs[3];
    const float mu = s * (1.f / 1024.f);
    float var = (sq - 1024.f * mu * mu) * (1.f / 1023.f);  // unbiased (ddof=1)
    var = fmaxf(var, 0.f);                                  // cancellation guard
    const float rstd = rsqrtf(var + 1e-5f);
    const float gm = bflo((u32)gs[0]);
    const float bt = bflo((u32)bs[0]);
    const float y0 = gm * (v0 - mu) * rstd + bt;
    const float y1 = gm * (v1 - mu) * rstd + bt;
    const float y2 = gm * (v2 - mu) * rstd + bt;
    const float y3 = gm * (v3 - mu) * rstd + bt;
    uint2 uo;
    uo.x = (u32)f2bf(y0) | ((u32)f2bf(y1) << 16);
    uo.y = (u32)f2bf(y2) | ((u32)f2bf(y3) << 16);
    *(uint2*)(out + (size_t)row * D_ + t * 4) = uo;
}

// ---------------------------------------------------------------------------
// GEMM: C[m,n] = sum_k A[m,k]*W[n,k] + bias[n] (+res) (relu?)  -- A:(M,K) W:(N,K)
// bf16 inputs, fp32 accum. Tile 128x128, BK=32, 256 threads (4 waves 2x2),
// each wave 64x64 via 4x4 of 16x16x32 MFMA. LDS rows padded to 40 elems (80 B).
// RES: 0 none, 1 bf16 residual, 2 fp32 residual.
// OUTF: 0 bf16 out, 1 fp32 out, 2 runtime (fp32 if *oflag else bf16).
// ---------------------------------------------------------------------------
template <int RELU, int RES, int OUTF>
__global__ __launch_bounds__(256, 2) void gemm_bt(const u16* __restrict__ A,
                                                  const u16* __restrict__ W,
                                                  const u16* __restrict__ bias,
                                                  const void* __restrict__ res,
                                                  void* __restrict__ out,
                                                  int M, int N, int K,
                                                  const int* __restrict__ oflag) {
    __shared__ __align__(16) u16 As[128 * 40];
    __shared__ __align__(16) u16 Bs[128 * 40];
    const int t = threadIdx.x;
    const int lane = t & 63, w = t >> 6;
    const int wm = w >> 1, wn = w & 1;
    const int m0 = blockIdx.y * 128, n0 = blockIdx.x * 128;

    f32x4 acc[4][4];
#pragma unroll
    for (int mi = 0; mi < 4; ++mi)
#pragma unroll
        for (int ni = 0; ni < 4; ++ni) acc[mi][ni] = (f32x4){0.f, 0.f, 0.f, 0.f};

    const int r1 = t >> 2, kc1 = t & 3;  // staging: row, k-chunk
    const u16* Ap = A + (size_t)(m0 + r1) * K + kc1 * 8;
    const u16* Bp = W + (size_t)(n0 + r1) * K + kc1 * 8;
    const size_t half_off = (size_t)64 * K;
    u16* As_w = &As[r1 * 40 + kc1 * 8];
    u16* Bs_w = &Bs[r1 * 40 + kc1 * 8];
    const u16* As_r = &As[(wm * 64 + (lane & 15)) * 40 + (lane >> 4) * 8];
    const u16* Bs_r = &Bs[(wn * 64 + (lane & 15)) * 40 + (lane >> 4) * 8];

    for (int kt = 0; kt < K; kt += 32) {
        uint4 a0 = *(const uint4*)(Ap + kt);
        uint4 a1 = *(const uint4*)(Ap + half_off + kt);
        uint4 b0 = *(const uint4*)(Bp + kt);
        uint4 b1 = *(const uint4*)(Bp + half_off + kt);
        __syncthreads();
        *(uint4*)As_w = a0;
        *(uint4*)(As_w + 64 * 40) = a1;
        *(uint4*)Bs_w = b0;
        *(uint4*)(Bs_w + 64 * 40) = b1;
        __syncthreads();
        bf16x8 af[4], bfr[4];
#pragma unroll
        for (int i = 0; i < 4; ++i) {
            af[i] = *(const bf16x8*)(As_r + i * 16 * 40);
            bfr[i] = *(const bf16x8*)(Bs_r + i * 16 * 40);
        }
#pragma unroll
        for (int mi = 0; mi < 4; ++mi)
#pragma unroll
            for (int ni = 0; ni < 4; ++ni)
                acc[mi][ni] = __builtin_amdgcn_mfma_f32_16x16x32_bf16(af[mi], bfr[ni], acc[mi][ni], 0, 0, 0);
    }

    const bool f32o = (OUTF == 1) || (OUTF == 2 && oflag[0] != 0);
    // epilogue. C/D layout: col = lane&15, row = (lane>>4)*4 + reg
    const int qd = lane >> 4, cl = lane & 15;
#pragma unroll
    for (int ni = 0; ni < 4; ++ni) {
        const int col = n0 + wn * 64 + ni * 16 + cl;
        const float bv = bflo((u32)bias[col]);
#pragma unroll
        for (int mi = 0; mi < 4; ++mi) {
#pragma unroll
            for (int j = 0; j < 4; ++j) {
                const int row = m0 + wm * 64 + mi * 16 + qd * 4 + j;
                float vv = acc[mi][ni][j] + bv;
                if (RELU) vv = fmaxf(vv, 0.f);
                if (RES == 1) vv += bflo((u32)((const u16*)res)[(size_t)row * N + col]);
                if (RES == 2) vv += ((const float*)res)[(size_t)row * N + col];
                if (f32o)
                    ((float*)out)[(size_t)row * N + col] = vv;
                else
                    ((u16*)out)[(size_t)row * N + col] = f2bf(vv);
            }
        }
    }
}

// ---------------------------------------------------------------------------
// Attention: per block = one (b,h) and 64 q-rows. Online softmax over 16
// K/V-tiles of 64 keys. Thread t: q-row r=t>>2, dim-group g=t&3 (16 dims).
// ---------------------------------------------------------------------------
__global__ __launch_bounds__(256, 2) void attn_kernel(const u16* __restrict__ Q,
                                                      const u16* __restrict__ Kg,
                                                      const u16* __restrict__ Vg,
                                                      u16* __restrict__ O) {
    __shared__ __align__(16) u16 Ks[64 * 72];
    __shared__ __align__(16) u16 Vs[64 * 72];
    __shared__ float s_tile[64 * 65];
    __shared__ float m_s[64], l_s[64], alpha_s[64];

    const int t = threadIdx.x;
    const int bh = blockIdx.y;
    const int b = bh >> 4, h = bh & 15;
    const int q0 = blockIdx.x * 64;
    const int r = t >> 2;  // q-row within tile
    const int g = t & 3;   // dim group

    float qr[64];
    {
        const u16* qp = Q + ((size_t)(b * S_ + q0 + r) * D_ + h * DK_);
#pragma unroll
        for (int c = 0; c < 8; ++c) {
            uint4 uq = *(const uint4*)(qp + c * 8);
            qr[c * 8 + 0] = bflo(uq.x); qr[c * 8 + 1] = bfhi(uq.x);
            qr[c * 8 + 2] = bflo(uq.y); qr[c * 8 + 3] = bfhi(uq.y);
            qr[c * 8 + 4] = bflo(uq.z); qr[c * 8 + 5] = bfhi(uq.z);
            qr[c * 8 + 6] = bflo(uq.w); qr[c * 8 + 7] = bfhi(uq.w);
        }
#pragma unroll
        for (int d = 0; d < 64; ++d) qr[d] *= 0.125f;
    }
    float oacc[16];
#pragma unroll
    for (int i = 0; i < 16; ++i) oacc[i] = 0.f;
    if (t < 64) { m_s[t] = -1e30f; l_s[t] = 0.f; }

    const size_t base_kv = (size_t)(b * S_) * D_ + h * DK_;
    for (int kt = 0; kt < 16; ++kt) {
        __syncthreads();
        {
            const u16* kp = Kg + base_kv + (size_t)(kt * 64 + r) * D_;
            const u16* vp = Vg + base_kv + (size_t)(kt * 64 + r) * D_;
            *(uint4*)&Ks[r * 72 + g * 16] = *(const uint4*)(kp + g * 16);
            *(uint4*)&Ks[r * 72 + g * 16 + 8] = *(const uint4*)(kp + g * 16 + 8);
            *(uint4*)&Vs[r * 72 + g * 16] = *(const uint4*)(vp + g * 16);
            *(uint4*)&Vs[r * 72 + g * 16 + 8] = *(const uint4*)(vp + g * 16 + 8);
        }
        __syncthreads();
        for (int kk = 0; kk < 16; ++kk) {
            const int k = kk * 4 + g;
            const u16* krow = &Ks[k * 72];
            float s = 0.f;
#pragma unroll
            for (int c = 0; c < 16; ++c) {
                uint2 u = *(const uint2*)(krow + c * 4);
                s = fmaf(qr[c * 4 + 0], bflo(u.x), s);
                s = fmaf(qr[c * 4 + 1], bfhi(u.x), s);
                s = fmaf(qr[c * 4 + 2], bflo(u.y), s);
                s = fmaf(qr[c * 4 + 3], bfhi(u.y), s);
            }
            s_tile[r * 65 + k] = s;
        }
        __syncthreads();
        if (t < 64) {
            const int rr = t;
            const float mo = m_s[rr];
            float mx = mo;
            for (int k = 0; k < 64; ++k) mx = fmaxf(mx, s_tile[rr * 65 + k]);
            const float al = __expf(mo - mx);
            float sum = 0.f;
            for (int k = 0; k < 64; ++k) {
                const float p = __expf(s_tile[rr * 65 + k] - mx);
                s_tile[rr * 65 + k] = p;
                sum += p;
            }
            l_s[rr] = l_s[rr] * al + sum;
            m_s[rr] = mx;
            alpha_s[rr] = al;
        }
        __syncthreads();
        {
            const float al = alpha_s[r];
#pragma unroll
            for (int i = 0; i < 16; ++i) oacc[i] *= al;
            for (int k = 0; k < 64; ++k) {
                const float p = s_tile[r * 65 + k];
                const u16* vrow = &Vs[k * 72 + g * 16];
#pragma unroll
                for (int c = 0; c < 4; ++c) {
                    uint2 u = *(const uint2*)(vrow + c * 4);
                    oacc[c * 4 + 0] = fmaf(p, bflo(u.x), oacc[c * 4 + 0]);
                    oacc[c * 4 + 1] = fmaf(p, bfhi(u.x), oacc[c * 4 + 1]);
                    oacc[c * 4 + 2] = fmaf(p, bflo(u.y), oacc[c * 4 + 2]);
                    oacc[c * 4 + 3] = fmaf(p, bfhi(u.y), oacc[c * 4 + 3]);
                }
            }
        }
    }
    __syncthreads();
    const float inv_l = 1.f / l_s[r];
    u16* op = O + ((size_t)(b * S_ + q0 + r) * D_ + h * DK_ + g * 16);
#pragma unroll
    for (int c = 0; c < 4; ++c) {
        uint2 uo;
        uo.x = (u32)f2bf(oacc[c * 4 + 0] * inv_l) | ((u32)f2bf(oacc[c * 4 + 1] * inv_l) << 16);
        uo.y = (u32)f2bf(oacc[c * 4 + 2] * inv_l) | ((u32)f2bf(oacc[c * 4 + 3] * inv_l) << 16);
        *(uint2*)(op + c * 4) = uo;
    }
}

// ---------------------------------------------------------------------------
extern "C" void kernel_launch(void* const* d_in, const int* in_sizes, int n_in,
                              void* d_out, int out_size, void* d_ws, size_t ws_size,
                              hipStream_t stream) {
    (void)in_sizes; (void)n_in; (void)out_size; (void)ws_size;
    char* ws = (char*)d_ws;
    const size_t MB = 1ull << 20;
    const size_t KB = 1024;
    // normalized bf16 inputs (persist whole pipeline): 0..41 MB
    u16* xn  = (u16*)(ws);
    u16* wqn = (u16*)(ws + 16 * MB);
    u16* wkn = (u16*)(ws + 18 * MB);
    u16* wvn = (u16*)(ws + 20 * MB);
    u16* won = (u16*)(ws + 22 * MB);
    u16* w1n = (u16*)(ws + 24 * MB);
    u16* w2n = (u16*)(ws + 32 * MB);
    u16* bqn = (u16*)(ws + 40 * MB);
    u16* bkn = (u16*)(ws + 40 * MB + 64 * KB);
    u16* bvn = (u16*)(ws + 40 * MB + 128 * KB);
    u16* bon = (u16*)(ws + 40 * MB + 192 * KB);
    u16* b1n = (u16*)(ws + 40 * MB + 256 * KB);
    u16* b2n = (u16*)(ws + 40 * MB + 320 * KB);
    u16* g1n = (u16*)(ws + 40 * MB + 384 * KB);
    u16* be1n= (u16*)(ws + 40 * MB + 448 * KB);
    u16* g2n = (u16*)(ws + 40 * MB + 512 * KB);
    u16* be2n= (u16*)(ws + 40 * MB + 576 * KB);
    int* flag= (int*)(ws + 40 * MB + 640 * KB);
    // pipeline buffers
    u16* h1  = (u16*)(ws + 48 * MB);   // ln1 out; attn out
    u16* qb  = (u16*)(ws + 64 * MB);
    u16* kb  = (u16*)(ws + 80 * MB);
    u16* vb  = (u16*)(ws + 96 * MB);
    float* x2 = (float*)(ws + 64 * MB); // overlays qb+kb (free after attn)
    u16* h2  = (u16*)(ws + 96 * MB);    // overlays vb (free after attn)
    u16* f1  = (u16*)(ws + 112 * MB);   // 64 MB -> total 176 MB

    const int M = B_ * S_;  // 8192

    sniff_kernel<<<1, 256, 0, stream>>>((const u16*)d_in[2], flag);
    auto nrm = [&](const void* in, u16* out, int n) {
        norm_kernel<<<(n + 255) / 256, 256, 0, stream>>>(in, out, n, flag);
    };
    nrm(d_in[0],  xn,  B_ * S_ * D_);
    nrm(d_in[2],  wqn, D_ * D_);
    nrm(d_in[3],  bqn, D_);
    nrm(d_in[4],  wkn, D_ * D_);
    nrm(d_in[5],  bkn, D_);
    nrm(d_in[6],  wvn, D_ * D_);
    nrm(d_in[7],  bvn, D_);
    nrm(d_in[8],  won, D_ * D_);
    nrm(d_in[9],  bon, D_);
    nrm(d_in[10], w1n, DFF_ * D_);
    nrm(d_in[11], b1n, DFF_);
    nrm(d_in[12], w2n, D_ * DFF_);
    nrm(d_in[13], b2n, D_);
    nrm(d_in[14], g1n, 1);
    nrm(d_in[15], be1n, 1);
    nrm(d_in[16], g2n, 1);
    nrm(d_in[17], be2n, 1);

    ln_kernel<0><<<M, 256, 0, stream>>>((const void*)xn, g1n, be1n, h1);
    gemm_bt<0, 0, 0><<<dim3(D_ / 128, M / 128), 256, 0, stream>>>(h1, wqn, bqn, nullptr, qb, M, D_, D_, nullptr);
    gemm_bt<0, 0, 0><<<dim3(D_ / 128, M / 128), 256, 0, stream>>>(h1, wkn, bkn, nullptr, kb, M, D_, D_, nullptr);
    gemm_bt<0, 0, 0><<<dim3(D_ / 128, M / 128), 256, 0, stream>>>(h1, wvn, bvn, nullptr, vb, M, D_, D_, nullptr);
    attn_kernel<<<dim3(S_ / 64, B_ * H_), 256, 0, stream>>>(qb, kb, vb, h1);
    gemm_bt<0, 1, 1><<<dim3(D_ / 128, M / 128), 256, 0, stream>>>(h1, won, bon, (const void*)xn, x2, M, D_, D_, nullptr);
    ln_kernel<1><<<M, 256, 0, stream>>>((const void*)x2, g2n, be2n, h2);
    gemm_bt<1, 0, 0><<<dim3(DFF_ / 128, M / 128), 256, 0, stream>>>(h2, w1n, b1n, nullptr, f1, M, DFF_, D_, nullptr);
    gemm_bt<0, 2, 2><<<dim3(D_ / 128, M / 128), 256, 0, stream>>>(f1, w2n, b2n, (const void*)x2, (void*)d_out, M, D_, DFF_, flag);
}

// Round 3
// 641.126 us; speedup vs baseline: 2.2902x; 2.2902x over previous
//
#include <hip/hip_runtime.h>

typedef unsigned short u16;
typedef unsigned int u32;
typedef __attribute__((ext_vector_type(8))) __bf16 bf16x8;
typedef __attribute__((ext_vector_type(4))) float f32x4;

#define B_ 8
#define S_ 1024
#define D_ 1024
#define H_ 16
#define DK_ 64
#define DFF_ 4096

__device__ __forceinline__ float bflo(u32 u) { return __uint_as_float(u << 16); }
__device__ __forceinline__ float bfhi(u32 u) { return __uint_as_float(u & 0xffff0000u); }
__device__ __forceinline__ u16 f2bf(float f) {
    u32 u = __float_as_uint(f);
    u += 0x7fffu + ((u >> 16) & 1u);   // RNE
    return (u16)(u >> 16);
}

// ---------------------------------------------------------------------------
// Dtype sniffer (validated round 2: inputs are fp32). Kept for safety.
// ---------------------------------------------------------------------------
__global__ __launch_bounds__(256) void sniff_kernel(const u16* __restrict__ w,
                                                    int* __restrict__ flag) {
    float mx = 0.f;
    for (int i = threadIdx.x; i < 4096; i += 256) {
        float v = fabsf(bflo((u32)w[i]));
        if (!isnan(v)) mx = fmaxf(mx, v);
    }
#pragma unroll
    for (int m = 1; m < 64; m <<= 1) mx = fmaxf(mx, __shfl_xor(mx, m, 64));
    __shared__ float wmx[4];
    if ((threadIdx.x & 63) == 0) wmx[threadIdx.x >> 6] = mx;
    __syncthreads();
    if (threadIdx.x == 0) {
        float m2 = fmaxf(fmaxf(wmx[0], wmx[1]), fmaxf(wmx[2], wmx[3]));
        *flag = (m2 > 1e3f) ? 1 : 0;
    }
}

__global__ __launch_bounds__(256) void norm_kernel(const void* __restrict__ in,
                                                   u16* __restrict__ out, int n,
                                                   const int* __restrict__ flag) {
    const int i = blockIdx.x * 256 + threadIdx.x;
    if (i >= n) return;
    if (*flag)
        out[i] = f2bf(((const float*)in)[i]);
    else
        out[i] = ((const u16*)in)[i];
}

// ---------------------------------------------------------------------------
// LayerNorm (ddof=1, scalar gamma/beta). One block per row of 1024.
// ---------------------------------------------------------------------------
template <int INF32>
__global__ __launch_bounds__(256) void ln_kernel(const void* __restrict__ in,
                                                 const u16* __restrict__ gs,
                                                 const u16* __restrict__ bs,
                                                 u16* __restrict__ out) {
    const int row = blockIdx.x, t = threadIdx.x;
    float v0, v1, v2, v3;
    if (INF32) {
        const float* p = (const float*)in + (size_t)row * D_ + t * 4;
        float4 f = *(const float4*)p;
        v0 = f.x; v1 = f.y; v2 = f.z; v3 = f.w;
    } else {
        const u16* p = (const u16*)in + (size_t)row * D_ + t * 4;
        uint2 u = *(const uint2*)p;
        v0 = bflo(u.x); v1 = bfhi(u.x); v2 = bflo(u.y); v3 = bfhi(u.y);
    }
    float s = v0 + v1 + v2 + v3;
    float sq = v0 * v0 + v1 * v1 + v2 * v2 + v3 * v3;
#pragma unroll
    for (int m = 1; m < 64; m <<= 1) {
        s += __shfl_xor(s, m, 64);
        sq += __shfl_xor(sq, m, 64);
    }
    __shared__ float ss[4], sqs[4];
    const int w = t >> 6;
    if ((t & 63) == 0) { ss[w] = s; sqs[w] = sq; }
    __syncthreads();
    s = ss[0] + ss[1] + ss[2] + ss[3];
    sq = sqs[0] + sqs[1] + sqs[2] + sqs[3];
    const float mu = s * (1.f / 1024.f);
    float var = (sq - 1024.f * mu * mu) * (1.f / 1023.f);
    var = fmaxf(var, 0.f);
    const float rstd = rsqrtf(var + 1e-5f);
    const float gm = bflo((u32)gs[0]);
    const float bt = bflo((u32)bs[0]);
    const float y0 = gm * (v0 - mu) * rstd + bt;
    const float y1 = gm * (v1 - mu) * rstd + bt;
    const float y2 = gm * (v2 - mu) * rstd + bt;
    const float y3 = gm * (v3 - mu) * rstd + bt;
    uint2 uo;
    uo.x = (u32)f2bf(y0) | ((u32)f2bf(y1) << 16);
    uo.y = (u32)f2bf(y2) | ((u32)f2bf(y3) << 16);
    *(uint2*)(out + (size_t)row * D_ + t * 4) = uo;
}

// ---------------------------------------------------------------------------
// GEMM (unchanged from round 2; validated at ~490 TF aggregate).
// ---------------------------------------------------------------------------
template <int RELU, int RES, int OUTF>
__global__ __launch_bounds__(256, 2) void gemm_bt(const u16* __restrict__ A,
                                                  const u16* __restrict__ W,
                                                  const u16* __restrict__ bias,
                                                  const void* __restrict__ res,
                                                  void* __restrict__ out,
                                                  int M, int N, int K,
                                                  const int* __restrict__ oflag) {
    __shared__ __align__(16) u16 As[128 * 40];
    __shared__ __align__(16) u16 Bs[128 * 40];
    const int t = threadIdx.x;
    const int lane = t & 63, w = t >> 6;
    const int wm = w >> 1, wn = w & 1;
    const int m0 = blockIdx.y * 128, n0 = blockIdx.x * 128;

    f32x4 acc[4][4];
#pragma unroll
    for (int mi = 0; mi < 4; ++mi)
#pragma unroll
        for (int ni = 0; ni < 4; ++ni) acc[mi][ni] = (f32x4){0.f, 0.f, 0.f, 0.f};

    const int r1 = t >> 2, kc1 = t & 3;
    const u16* Ap = A + (size_t)(m0 + r1) * K + kc1 * 8;
    const u16* Bp = W + (size_t)(n0 + r1) * K + kc1 * 8;
    const size_t half_off = (size_t)64 * K;
    u16* As_w = &As[r1 * 40 + kc1 * 8];
    u16* Bs_w = &Bs[r1 * 40 + kc1 * 8];
    const u16* As_r = &As[(wm * 64 + (lane & 15)) * 40 + (lane >> 4) * 8];
    const u16* Bs_r = &Bs[(wn * 64 + (lane & 15)) * 40 + (lane >> 4) * 8];

    for (int kt = 0; kt < K; kt += 32) {
        uint4 a0 = *(const uint4*)(Ap + kt);
        uint4 a1 = *(const uint4*)(Ap + half_off + kt);
        uint4 b0 = *(const uint4*)(Bp + kt);
        uint4 b1 = *(const uint4*)(Bp + half_off + kt);
        __syncthreads();
        *(uint4*)As_w = a0;
        *(uint4*)(As_w + 64 * 40) = a1;
        *(uint4*)Bs_w = b0;
        *(uint4*)(Bs_w + 64 * 40) = b1;
        __syncthreads();
        bf16x8 af[4], bfr[4];
#pragma unroll
        for (int i = 0; i < 4; ++i) {
            af[i] = *(const bf16x8*)(As_r + i * 16 * 40);
            bfr[i] = *(const bf16x8*)(Bs_r + i * 16 * 40);
        }
#pragma unroll
        for (int mi = 0; mi < 4; ++mi)
#pragma unroll
            for (int ni = 0; ni < 4; ++ni)
                acc[mi][ni] = __builtin_amdgcn_mfma_f32_16x16x32_bf16(af[mi], bfr[ni], acc[mi][ni], 0, 0, 0);
    }

    const bool f32o = (OUTF == 1) || (OUTF == 2 && oflag[0] != 0);
    const int qd = lane >> 4, cl = lane & 15;
#pragma unroll
    for (int ni = 0; ni < 4; ++ni) {
        const int col = n0 + wn * 64 + ni * 16 + cl;
        const float bv = bflo((u32)bias[col]);
#pragma unroll
        for (int mi = 0; mi < 4; ++mi) {
#pragma unroll
            for (int j = 0; j < 4; ++j) {
                const int row = m0 + wm * 64 + mi * 16 + qd * 4 + j;
                float vv = acc[mi][ni][j] + bv;
                if (RELU) vv = fmaxf(vv, 0.f);
                if (RES == 1) vv += bflo((u32)((const u16*)res)[(size_t)row * N + col]);
                if (RES == 2) vv += ((const float*)res)[(size_t)row * N + col];
                if (f32o)
                    ((float*)out)[(size_t)row * N + col] = vv;
                else
                    ((u16*)out)[(size_t)row * N + col] = f2bf(vv);
            }
        }
    }
}

// ---------------------------------------------------------------------------
// MFMA flash attention. Block = (b,h) x 256 q-rows; wave w owns 64 q-rows.
// S^T = K·Q^T (A=K from LDS, B=Q from regs) -> q lands on lane&15 in C-layout.
// Softmax in exp2 domain (scale 0.125*log2e folded in); stats per-lane.
// P^T regs -> LDS [q][k-contig] via b64 vector writes (per-wave buffer).
// O^T = V^T·P (A=V^T staged transposed, B=P) -> q on lane&15 again, so
// alpha/l apply lane-locally; j indexes consecutive d -> 8B packed stores.
// LDS 54KB -> 2 blocks/CU; grid 512 = exactly resident.
// ---------------------------------------------------------------------------
__global__ __launch_bounds__(256, 2) void attn_mfma(const u16* __restrict__ Q,
                                                    const u16* __restrict__ Kg,
                                                    const u16* __restrict__ Vg,
                                                    u16* __restrict__ O) {
    __shared__ __align__(16) u16 lds[6 * 64 * 72];  // Ks | VsT | P x4 waves
    u16* Ks = lds;
    u16* VsT = lds + 64 * 72;

    const int t = threadIdx.x;
    const int lane = t & 63, w = t >> 6;
    u16* Pw = lds + (2 + w) * 64 * 72;
    const int b = blockIdx.y >> 4, h = blockIdx.y & 15;
    const int q_base = blockIdx.x * 256 + w * 64;
    const int c = lane & 15, g = lane >> 4;
    const float SC = 0.18033688011112042f;  // (1/8)*log2(e)

    // preload Q B-frags: qfrag[ni][kc] -> Q[q=16ni+c][d=kc*32+8g .. +7]
    bf16x8 qfrag[4][2];
#pragma unroll
    for (int ni = 0; ni < 4; ++ni)
#pragma unroll
        for (int kc = 0; kc < 2; ++kc)
            qfrag[ni][kc] = *(const bf16x8*)(Q + (size_t)(b * S_ + q_base + 16 * ni + c) * D_ +
                                             h * 64 + kc * 32 + 8 * g);

    f32x4 acc_o[4][4];
#pragma unroll
    for (int mi = 0; mi < 4; ++mi)
#pragma unroll
        for (int ni = 0; ni < 4; ++ni) acc_o[mi][ni] = (f32x4){0.f, 0.f, 0.f, 0.f};
    float m_st[4] = {-1e30f, -1e30f, -1e30f, -1e30f};
    float l_st[4] = {0.f, 0.f, 0.f, 0.f};

    const size_t kv0 = (size_t)(b * S_) * D_ + h * 64;
    const int srow = t >> 2, sc4 = t & 3;  // staging: key-row, 16-col chunk

    for (int kt = 0; kt < 16; ++kt) {
        __syncthreads();  // all waves done reading Ks/VsT of prev tile
        {
            const u16* kp = Kg + kv0 + (size_t)(kt * 64 + srow) * D_ + sc4 * 16;
            uint4 k0 = *(const uint4*)kp;
            uint4 k1 = *(const uint4*)(kp + 8);
            *(uint4*)&Ks[srow * 72 + sc4 * 16] = k0;
            *(uint4*)&Ks[srow * 72 + sc4 * 16 + 8] = k1;
            const u16* vp = Vg + kv0 + (size_t)(kt * 64 + srow) * D_ + sc4 * 16;
            uint4 v0 = *(const uint4*)vp;
            uint4 v1 = *(const uint4*)(vp + 8);
            u32 vw[8] = {v0.x, v0.y, v0.z, v0.w, v1.x, v1.y, v1.z, v1.w};
#pragma unroll
            for (int i = 0; i < 8; ++i) {  // transpose V into VsT[d][key]
                VsT[(sc4 * 16 + 2 * i) * 72 + srow] = (u16)(vw[i] & 0xffffu);
                VsT[(sc4 * 16 + 2 * i + 1) * 72 + srow] = (u16)(vw[i] >> 16);
            }
        }
        __syncthreads();

        // S^T = K·Q^T : acc_s[mi][ni], key = 16mi+4g+j, q = 16ni+c
        f32x4 acc_s[4][4];
#pragma unroll
        for (int mi = 0; mi < 4; ++mi)
#pragma unroll
            for (int ni = 0; ni < 4; ++ni) acc_s[mi][ni] = (f32x4){0.f, 0.f, 0.f, 0.f};
#pragma unroll
        for (int kc = 0; kc < 2; ++kc) {
            bf16x8 kf[4];
#pragma unroll
            for (int mi = 0; mi < 4; ++mi)
                kf[mi] = *(const bf16x8*)&Ks[(16 * mi + c) * 72 + kc * 32 + 8 * g];
#pragma unroll
            for (int mi = 0; mi < 4; ++mi)
#pragma unroll
                for (int ni = 0; ni < 4; ++ni)
                    acc_s[mi][ni] = __builtin_amdgcn_mfma_f32_16x16x32_bf16(
                        kf[mi], qfrag[ni][kc], acc_s[mi][ni], 0, 0, 0);
        }

        // online softmax per q (= lane&15 within each ni tile), exp2 domain
        float alpha[4];
#pragma unroll
        for (int ni = 0; ni < 4; ++ni) {
            float mx = -1e30f;
#pragma unroll
            for (int mi = 0; mi < 4; ++mi) {
#pragma unroll
                for (int j = 0; j < 4; ++j) {
                    acc_s[mi][ni][j] *= SC;
                    mx = fmaxf(mx, acc_s[mi][ni][j]);
                }
            }
            mx = fmaxf(mx, __shfl_xor(mx, 16, 64));
            mx = fmaxf(mx, __shfl_xor(mx, 32, 64));
            const float mn = fmaxf(m_st[ni], mx);
            alpha[ni] = exp2f(m_st[ni] - mn);
            m_st[ni] = mn;
            float sum = 0.f;
#pragma unroll
            for (int mi = 0; mi < 4; ++mi) {
                float p0 = exp2f(acc_s[mi][ni][0] - mn);
                float p1 = exp2f(acc_s[mi][ni][1] - mn);
                float p2 = exp2f(acc_s[mi][ni][2] - mn);
                float p3 = exp2f(acc_s[mi][ni][3] - mn);
                sum += (p0 + p1) + (p2 + p3);
                uint2 pk;
                pk.x = (u32)f2bf(p0) | ((u32)f2bf(p1) << 16);
                pk.y = (u32)f2bf(p2) | ((u32)f2bf(p3) << 16);
                // P[q=16ni+c][k=16mi+4g .. +3]
                *(uint2*)&Pw[(16 * ni + c) * 72 + 16 * mi + 4 * g] = pk;
            }
            sum += __shfl_xor(sum, 16, 64);
            sum += __shfl_xor(sum, 32, 64);
            l_st[ni] = l_st[ni] * alpha[ni] + sum;
        }
#pragma unroll
        for (int mi = 0; mi < 4; ++mi)
#pragma unroll
            for (int ni = 0; ni < 4; ++ni) {
#pragma unroll
                for (int j = 0; j < 4; ++j) acc_o[mi][ni][j] *= alpha[ni];
            }

        // O^T += V^T·P : A=V^T[d][k], B=P[q][k] (both k-contig vector reads)
#pragma unroll
        for (int kc = 0; kc < 2; ++kc) {
            bf16x8 vf[4], pf[4];
#pragma unroll
            for (int mi = 0; mi < 4; ++mi)
                vf[mi] = *(const bf16x8*)&VsT[(16 * mi + c) * 72 + kc * 32 + 8 * g];
#pragma unroll
            for (int ni = 0; ni < 4; ++ni)
                pf[ni] = *(const bf16x8*)&Pw[(16 * ni + c) * 72 + kc * 32 + 8 * g];
#pragma unroll
            for (int mi = 0; mi < 4; ++mi)
#pragma unroll
                for (int ni = 0; ni < 4; ++ni)
                    acc_o[mi][ni] = __builtin_amdgcn_mfma_f32_16x16x32_bf16(
                        vf[mi], pf[ni], acc_o[mi][ni], 0, 0, 0);
        }
    }

    // epilogue: O[q][d] = acc_o^T / l ; q = q_base+16ni+c, d = 16mi+4g+j
#pragma unroll
    for (int ni = 0; ni < 4; ++ni) {
        const float inv_l = 1.f / l_st[ni];
        u16* op = O + (size_t)(b * S_ + q_base + 16 * ni + c) * D_ + h * 64;
#pragma unroll
        for (int mi = 0; mi < 4; ++mi) {
            uint2 uo;
            uo.x = (u32)f2bf(acc_o[mi][ni][0] * inv_l) |
                   ((u32)f2bf(acc_o[mi][ni][1] * inv_l) << 16);
            uo.y = (u32)f2bf(acc_o[mi][ni][2] * inv_l) |
                   ((u32)f2bf(acc_o[mi][ni][3] * inv_l) << 16);
            *(uint2*)(op + 16 * mi + 4 * g) = uo;
        }
    }
}

// ---------------------------------------------------------------------------
extern "C" void kernel_launch(void* const* d_in, const int* in_sizes, int n_in,
                              void* d_out, int out_size, void* d_ws, size_t ws_size,
                              hipStream_t stream) {
    (void)in_sizes; (void)n_in; (void)out_size; (void)ws_size;
    char* ws = (char*)d_ws;
    const size_t MB = 1ull << 20;
    const size_t KB = 1024;
    u16* xn  = (u16*)(ws);
    u16* wqn = (u16*)(ws + 16 * MB);
    u16* wkn = (u16*)(ws + 18 * MB);
    u16* wvn = (u16*)(ws + 20 * MB);
    u16* won = (u16*)(ws + 22 * MB);
    u16* w1n = (u16*)(ws + 24 * MB);
    u16* w2n = (u16*)(ws + 32 * MB);
    u16* bqn = (u16*)(ws + 40 * MB);
    u16* bkn = (u16*)(ws + 40 * MB + 64 * KB);
    u16* bvn = (u16*)(ws + 40 * MB + 128 * KB);
    u16* bon = (u16*)(ws + 40 * MB + 192 * KB);
    u16* b1n = (u16*)(ws + 40 * MB + 256 * KB);
    u16* b2n = (u16*)(ws + 40 * MB + 320 * KB);
    u16* g1n = (u16*)(ws + 40 * MB + 384 * KB);
    u16* be1n= (u16*)(ws + 40 * MB + 448 * KB);
    u16* g2n = (u16*)(ws + 40 * MB + 512 * KB);
    u16* be2n= (u16*)(ws + 40 * MB + 576 * KB);
    int* flag= (int*)(ws + 40 * MB + 640 * KB);
    u16* h1  = (u16*)(ws + 48 * MB);
    u16* qb  = (u16*)(ws + 64 * MB);
    u16* kb  = (u16*)(ws + 80 * MB);
    u16* vb  = (u16*)(ws + 96 * MB);
    float* x2 = (float*)(ws + 64 * MB);
    u16* h2  = (u16*)(ws + 96 * MB);
    u16* f1  = (u16*)(ws + 112 * MB);

    const int M = B_ * S_;  // 8192

    sniff_kernel<<<1, 256, 0, stream>>>((const u16*)d_in[2], flag);
    auto nrm = [&](const void* in, u16* out, int n) {
        norm_kernel<<<(n + 255) / 256, 256, 0, stream>>>(in, out, n, flag);
    };
    nrm(d_in[0],  xn,  B_ * S_ * D_);
    nrm(d_in[2],  wqn, D_ * D_);
    nrm(d_in[3],  bqn, D_);
    nrm(d_in[4],  wkn, D_ * D_);
    nrm(d_in[5],  bkn, D_);
    nrm(d_in[6],  wvn, D_ * D_);
    nrm(d_in[7],  bvn, D_);
    nrm(d_in[8],  won, D_ * D_);
    nrm(d_in[9],  bon, D_);
    nrm(d_in[10], w1n, DFF_ * D_);
    nrm(d_in[11], b1n, DFF_);
    nrm(d_in[12], w2n, D_ * DFF_);
    nrm(d_in[13], b2n, D_);
    nrm(d_in[14], g1n, 1);
    nrm(d_in[15], be1n, 1);
    nrm(d_in[16], g2n, 1);
    nrm(d_in[17], be2n, 1);

    ln_kernel<0><<<M, 256, 0, stream>>>((const void*)xn, g1n, be1n, h1);
    gemm_bt<0, 0, 0><<<dim3(D_ / 128, M / 128), 256, 0, stream>>>(h1, wqn, bqn, nullptr, qb, M, D_, D_, nullptr);
    gemm_bt<0, 0, 0><<<dim3(D_ / 128, M / 128), 256, 0, stream>>>(h1, wkn, bkn, nullptr, kb, M, D_, D_, nullptr);
    gemm_bt<0, 0, 0><<<dim3(D_ / 128, M / 128), 256, 0, stream>>>(h1, wvn, bvn, nullptr, vb, M, D_, D_, nullptr);
    attn_mfma<<<dim3(S_ / 256, B_ * H_), 256, 0, stream>>>(qb, kb, vb, h1);
    gemm_bt<0, 1, 1><<<dim3(D_ / 128, M / 128), 256, 0, stream>>>(h1, won, bon, (const void*)xn, x2, M, D_, D_, nullptr);
    ln_kernel<1><<<M, 256, 0, stream>>>((const void*)x2, g2n, be2n, h2);
    gemm_bt<1, 0, 0><<<dim3(DFF_ / 128, M / 128), 256, 0, stream>>>(h2, w1n, b1n, nullptr, f1, M, DFF_, D_, nullptr);
    gemm_bt<0, 2, 2><<<dim3(D_ / 128, M / 128), 256, 0, stream>>>(f1, w2n, b2n, (const void*)x2, (void*)d_out, M, D_, DFF_, flag);
}

// Round 4
// 588.597 us; speedup vs baseline: 2.4946x; 1.0892x over previous
//
#include <hip/hip_runtime.h>

typedef unsigned short u16;
typedef unsigned int u32;
typedef __attribute__((ext_vector_type(8))) __bf16 bf16x8;
typedef __attribute__((ext_vector_type(4))) float f32x4;

#define B_ 8
#define S_ 1024
#define D_ 1024
#define H_ 16
#define DK_ 64
#define DFF_ 4096
#define LDQKV 3072

__device__ __forceinline__ float bflo(u32 u) { return __uint_as_float(u << 16); }
__device__ __forceinline__ float bfhi(u32 u) { return __uint_as_float(u & 0xffff0000u); }
__device__ __forceinline__ u16 f2bf(float f) {
    u32 u = __float_as_uint(f);
    u += 0x7fffu + ((u >> 16) & 1u);   // RNE
    return (u16)(u >> 16);
}

// async global->LDS DMA, 16B per lane; LDS dest = wave-uniform base + lane*16
__device__ __forceinline__ void gl2lds16(const u16* g, u16* l) {
    __builtin_amdgcn_global_load_lds(
        (const __attribute__((address_space(1))) void*)g,
        (__attribute__((address_space(3))) void*)l, 16, 0, 0);
}

// ---------------------------------------------------------------------------
// Dtype sniffer (validated round 2: inputs are fp32). Kept for safety.
// ---------------------------------------------------------------------------
__global__ __launch_bounds__(256) void sniff_kernel(const u16* __restrict__ w,
                                                    int* __restrict__ flag) {
    float mx = 0.f;
    for (int i = threadIdx.x; i < 4096; i += 256) {
        float v = fabsf(bflo((u32)w[i]));
        if (!isnan(v)) mx = fmaxf(mx, v);
    }
#pragma unroll
    for (int m = 1; m < 64; m <<= 1) mx = fmaxf(mx, __shfl_xor(mx, m, 64));
    __shared__ float wmx[4];
    if ((threadIdx.x & 63) == 0) wmx[threadIdx.x >> 6] = mx;
    __syncthreads();
    if (threadIdx.x == 0) {
        float m2 = fmaxf(fmaxf(wmx[0], wmx[1]), fmaxf(wmx[2], wmx[3]));
        *flag = (m2 > 1e3f) ? 1 : 0;
    }
}

__global__ __launch_bounds__(256) void norm_kernel(const void* __restrict__ in,
                                                   u16* __restrict__ out, int n,
                                                   const int* __restrict__ flag) {
    const int i = blockIdx.x * 256 + threadIdx.x;
    if (i >= n) return;
    if (*flag)
        out[i] = f2bf(((const float*)in)[i]);
    else
        out[i] = ((const u16*)in)[i];
}

// fused conversion of the 10 small tensors (biases + scalars) in one dispatch
struct SmallTbl {
    const void* src[10];
    u16* dst[10];
    int n[10];
};
__global__ __launch_bounds__(256) void norm_small(SmallTbl tb,
                                                  const int* __restrict__ flag) {
    int i = blockIdx.x * 256 + threadIdx.x;
    const int f = *flag;
#pragma unroll
    for (int j = 0; j < 10; ++j) {
        if (i < tb.n[j]) {
            if (f)
                tb.dst[j][i] = f2bf(((const float*)tb.src[j])[i]);
            else
                tb.dst[j][i] = ((const u16*)tb.src[j])[i];
            return;
        }
        i -= tb.n[j];
    }
}

// ---------------------------------------------------------------------------
// LayerNorm (ddof=1, scalar gamma/beta). One block per row of 1024.
// ---------------------------------------------------------------------------
template <int INF32>
__global__ __launch_bounds__(256) void ln_kernel(const void* __restrict__ in,
                                                 const u16* __restrict__ gs,
                                                 const u16* __restrict__ bs,
                                                 u16* __restrict__ out) {
    const int row = blockIdx.x, t = threadIdx.x;
    float v0, v1, v2, v3;
    if (INF32) {
        const float* p = (const float*)in + (size_t)row * D_ + t * 4;
        float4 f = *(const float4*)p;
        v0 = f.x; v1 = f.y; v2 = f.z; v3 = f.w;
    } else {
        const u16* p = (const u16*)in + (size_t)row * D_ + t * 4;
        uint2 u = *(const uint2*)p;
        v0 = bflo(u.x); v1 = bfhi(u.x); v2 = bflo(u.y); v3 = bfhi(u.y);
    }
    float s = v0 + v1 + v2 + v3;
    float sq = v0 * v0 + v1 * v1 + v2 * v2 + v3 * v3;
#pragma unroll
    for (int m = 1; m < 64; m <<= 1) {
        s += __shfl_xor(s, m, 64);
        sq += __shfl_xor(sq, m, 64);
    }
    __shared__ float ss[4], sqs[4];
    const int w = t >> 6;
    if ((t & 63) == 0) { ss[w] = s; sqs[w] = sq; }
    __syncthreads();
    s = ss[0] + ss[1] + ss[2] + ss[3];
    sq = sqs[0] + sqs[1] + sqs[2] + sqs[3];
    const float mu = s * (1.f / 1024.f);
    float var = (sq - 1024.f * mu * mu) * (1.f / 1023.f);
    var = fmaxf(var, 0.f);
    const float rstd = rsqrtf(var + 1e-5f);
    const float gm = bflo((u32)gs[0]);
    const float bt = bflo((u32)bs[0]);
    const float y0 = gm * (v0 - mu) * rstd + bt;
    const float y1 = gm * (v1 - mu) * rstd + bt;
    const float y2 = gm * (v2 - mu) * rstd + bt;
    const float y3 = gm * (v3 - mu) * rstd + bt;
    uint2 uo;
    uo.x = (u32)f2bf(y0) | ((u32)f2bf(y1) << 16);
    uo.y = (u32)f2bf(y2) | ((u32)f2bf(y3) << 16);
    *(uint2*)(out + (size_t)row * D_ + t * 4) = uo;
}

// ---------------------------------------------------------------------------
// GEMM, m97 structure: global_load_lds width-16 staging into UNPADDED
// 128x32 LDS tiles (DMA dest is wave-uniform base + lane*16B -> layout must
// be contiguous in lane order; no padding possible). 2-barrier K-loop.
// Tile 128x128, BK=32, 4 waves 2x2, wave = 64x64 via 4x4 16x16x32 MFMA.
// RES: 0 none, 1 bf16 residual, 2 fp32 residual.
// OUTF: 0 bf16 out, 1 fp32 out, 2 runtime (fp32 if *oflag else bf16).
// ---------------------------------------------------------------------------
template <int RELU, int RES, int OUTF>
__global__ __launch_bounds__(256, 2) void gemm_bt(const u16* __restrict__ A,
                                                  const u16* __restrict__ W,
                                                  const u16* __restrict__ bias,
                                                  const void* __restrict__ res,
                                                  void* __restrict__ out,
                                                  int M, int N, int K,
                                                  const int* __restrict__ oflag) {
    __shared__ __align__(16) u16 As[128 * 32];
    __shared__ __align__(16) u16 Bs[128 * 32];
    const int t = threadIdx.x;
    const int lane = t & 63, w = t >> 6;
    const int wm = w >> 1, wn = w & 1;
    const int m0 = blockIdx.y * 128, n0 = blockIdx.x * 128;

    f32x4 acc[4][4];
#pragma unroll
    for (int mi = 0; mi < 4; ++mi)
#pragma unroll
        for (int ni = 0; ni < 4; ++ni) acc[mi][ni] = (f32x4){0.f, 0.f, 0.f, 0.f};

    // staging: wave w DMAs 16-row groups at rows {w*16, 64+w*16} of A and B.
    // lane l covers row base+l/4, k-chunk (l&3)*8; LDS lands at base+l*16B
    // which equals row-major [row][32] exactly (l/4*32 + (l&3)*8 == 8*l).
    const int sr = lane >> 2, skc = lane & 3;
    const u16* Ag0 = A + (size_t)(m0 + w * 16 + sr) * K + skc * 8;
    const u16* Bg0 = W + (size_t)(n0 + w * 16 + sr) * K + skc * 8;
    const size_t h64 = (size_t)64 * K;
    u16* Asd0 = &As[(w * 16) * 32];
    u16* Asd1 = &As[(64 + w * 16) * 32];
    u16* Bsd0 = &Bs[(w * 16) * 32];
    u16* Bsd1 = &Bs[(64 + w * 16) * 32];

    const u16* As_r = &As[(wm * 64 + (lane & 15)) * 32 + (lane >> 4) * 8];
    const u16* Bs_r = &Bs[(wn * 64 + (lane & 15)) * 32 + (lane >> 4) * 8];

    for (int kt = 0; kt < K; kt += 32) {
        __syncthreads();  // all waves done reading prev tile
        gl2lds16(Ag0 + kt, Asd0);
        gl2lds16(Ag0 + h64 + kt, Asd1);
        gl2lds16(Bg0 + kt, Bsd0);
        gl2lds16(Bg0 + h64 + kt, Bsd1);
        __syncthreads();  // drains vmcnt -> DMA'd data visible
        bf16x8 af[4], bfr[4];
#pragma unroll
        for (int i = 0; i < 4; ++i) {
            af[i] = *(const bf16x8*)(As_r + i * 16 * 32);
            bfr[i] = *(const bf16x8*)(Bs_r + i * 16 * 32);
        }
#pragma unroll
        for (int mi = 0; mi < 4; ++mi)
#pragma unroll
            for (int ni = 0; ni < 4; ++ni)
                acc[mi][ni] = __builtin_amdgcn_mfma_f32_16x16x32_bf16(af[mi], bfr[ni], acc[mi][ni], 0, 0, 0);
    }

    const bool f32o = (OUTF == 1) || (OUTF == 2 && oflag[0] != 0);
    const int qd = lane >> 4, cl = lane & 15;
#pragma unroll
    for (int ni = 0; ni < 4; ++ni) {
        const int col = n0 + wn * 64 + ni * 16 + cl;
        const float bv = bflo((u32)bias[col]);
#pragma unroll
        for (int mi = 0; mi < 4; ++mi) {
#pragma unroll
            for (int j = 0; j < 4; ++j) {
                const int row = m0 + wm * 64 + mi * 16 + qd * 4 + j;
                float vv = acc[mi][ni][j] + bv;
                if (RELU) vv = fmaxf(vv, 0.f);
                if (RES == 1) vv += bflo((u32)((const u16*)res)[(size_t)row * N + col]);
                if (RES == 2) vv += ((const float*)res)[(size_t)row * N + col];
                if (f32o)
                    ((float*)out)[(size_t)row * N + col] = vv;
                else
                    ((u16*)out)[(size_t)row * N + col] = f2bf(vv);
            }
        }
    }
}

// ---------------------------------------------------------------------------
// MFMA flash attention over the fused QKV buffer (row stride LDQKV=3072;
// Q at +0, K at +1024, V at +2048). Structure validated round 3.
// ---------------------------------------------------------------------------
__global__ __launch_bounds__(256, 2) void attn_mfma(const u16* __restrict__ QKV,
                                                    u16* __restrict__ O) {
    __shared__ __align__(16) u16 lds[6 * 64 * 72];  // Ks | VsT | P x4 waves
    u16* Ks = lds;
    u16* VsT = lds + 64 * 72;

    const int t = threadIdx.x;
    const int lane = t & 63, w = t >> 6;
    u16* Pw = lds + (2 + w) * 64 * 72;
    const int b = blockIdx.y >> 4, h = blockIdx.y & 15;
    const int q_base = blockIdx.x * 256 + w * 64;
    const int c = lane & 15, g = lane >> 4;
    const float SC = 0.18033688011112042f;  // (1/8)*log2(e)

    bf16x8 qfrag[4][2];
#pragma unroll
    for (int ni = 0; ni < 4; ++ni)
#pragma unroll
        for (int kc = 0; kc < 2; ++kc)
            qfrag[ni][kc] = *(const bf16x8*)(QKV + (size_t)(b * S_ + q_base + 16 * ni + c) * LDQKV +
                                             h * 64 + kc * 32 + 8 * g);

    f32x4 acc_o[4][4];
#pragma unroll
    for (int mi = 0; mi < 4; ++mi)
#pragma unroll
        for (int ni = 0; ni < 4; ++ni) acc_o[mi][ni] = (f32x4){0.f, 0.f, 0.f, 0.f};
    float m_st[4] = {-1e30f, -1e30f, -1e30f, -1e30f};
    float l_st[4] = {0.f, 0.f, 0.f, 0.f};

    const size_t kbase = (size_t)(b * S_) * LDQKV + 1024 + h * 64;
    const size_t vbase = (size_t)(b * S_) * LDQKV + 2048 + h * 64;
    const int srow = t >> 2, sc4 = t & 3;

    for (int kt = 0; kt < 16; ++kt) {
        __syncthreads();
        {
            const u16* kp = QKV + kbase + (size_t)(kt * 64 + srow) * LDQKV + sc4 * 16;
            uint4 k0 = *(const uint4*)kp;
            uint4 k1 = *(const uint4*)(kp + 8);
            *(uint4*)&Ks[srow * 72 + sc4 * 16] = k0;
            *(uint4*)&Ks[srow * 72 + sc4 * 16 + 8] = k1;
            const u16* vp = QKV + vbase + (size_t)(kt * 64 + srow) * LDQKV + sc4 * 16;
            uint4 v0 = *(const uint4*)vp;
            uint4 v1 = *(const uint4*)(vp + 8);
            u32 vw[8] = {v0.x, v0.y, v0.z, v0.w, v1.x, v1.y, v1.z, v1.w};
#pragma unroll
            for (int i = 0; i < 8; ++i) {
                VsT[(sc4 * 16 + 2 * i) * 72 + srow] = (u16)(vw[i] & 0xffffu);
                VsT[(sc4 * 16 + 2 * i + 1) * 72 + srow] = (u16)(vw[i] >> 16);
            }
        }
        __syncthreads();

        f32x4 acc_s[4][4];
#pragma unroll
        for (int mi = 0; mi < 4; ++mi)
#pragma unroll
            for (int ni = 0; ni < 4; ++ni) acc_s[mi][ni] = (f32x4){0.f, 0.f, 0.f, 0.f};
#pragma unroll
        for (int kc = 0; kc < 2; ++kc) {
            bf16x8 kf[4];
#pragma unroll
            for (int mi = 0; mi < 4; ++mi)
                kf[mi] = *(const bf16x8*)&Ks[(16 * mi + c) * 72 + kc * 32 + 8 * g];
#pragma unroll
            for (int mi = 0; mi < 4; ++mi)
#pragma unroll
                for (int ni = 0; ni < 4; ++ni)
                    acc_s[mi][ni] = __builtin_amdgcn_mfma_f32_16x16x32_bf16(
                        kf[mi], qfrag[ni][kc], acc_s[mi][ni], 0, 0, 0);
        }

        float alpha[4];
#pragma unroll
        for (int ni = 0; ni < 4; ++ni) {
            float mx = -1e30f;
#pragma unroll
            for (int mi = 0; mi < 4; ++mi) {
#pragma unroll
                for (int j = 0; j < 4; ++j) {
                    acc_s[mi][ni][j] *= SC;
                    mx = fmaxf(mx, acc_s[mi][ni][j]);
                }
            }
            mx = fmaxf(mx, __shfl_xor(mx, 16, 64));
            mx = fmaxf(mx, __shfl_xor(mx, 32, 64));
            const float mn = fmaxf(m_st[ni], mx);
            alpha[ni] = exp2f(m_st[ni] - mn);
            m_st[ni] = mn;
            float sum = 0.f;
#pragma unroll
            for (int mi = 0; mi < 4; ++mi) {
                float p0 = exp2f(acc_s[mi][ni][0] - mn);
                float p1 = exp2f(acc_s[mi][ni][1] - mn);
                float p2 = exp2f(acc_s[mi][ni][2] - mn);
                float p3 = exp2f(acc_s[mi][ni][3] - mn);
                sum += (p0 + p1) + (p2 + p3);
                uint2 pk;
                pk.x = (u32)f2bf(p0) | ((u32)f2bf(p1) << 16);
                pk.y = (u32)f2bf(p2) | ((u32)f2bf(p3) << 16);
                *(uint2*)&Pw[(16 * ni + c) * 72 + 16 * mi + 4 * g] = pk;
            }
            sum += __shfl_xor(sum, 16, 64);
            sum += __shfl_xor(sum, 32, 64);
            l_st[ni] = l_st[ni] * alpha[ni] + sum;
        }
#pragma unroll
        for (int mi = 0; mi < 4; ++mi)
#pragma unroll
            for (int ni = 0; ni < 4; ++ni) {
#pragma unroll
                for (int j = 0; j < 4; ++j) acc_o[mi][ni][j] *= alpha[ni];
            }

#pragma unroll
        for (int kc = 0; kc < 2; ++kc) {
            bf16x8 vf[4], pf[4];
#pragma unroll
            for (int mi = 0; mi < 4; ++mi)
                vf[mi] = *(const bf16x8*)&VsT[(16 * mi + c) * 72 + kc * 32 + 8 * g];
#pragma unroll
            for (int ni = 0; ni < 4; ++ni)
                pf[ni] = *(const bf16x8*)&Pw[(16 * ni + c) * 72 + kc * 32 + 8 * g];
#pragma unroll
            for (int mi = 0; mi < 4; ++mi)
#pragma unroll
                for (int ni = 0; ni < 4; ++ni)
                    acc_o[mi][ni] = __builtin_amdgcn_mfma_f32_16x16x32_bf16(
                        vf[mi], pf[ni], acc_o[mi][ni], 0, 0, 0);
        }
    }

#pragma unroll
    for (int ni = 0; ni < 4; ++ni) {
        const float inv_l = 1.f / l_st[ni];
        u16* op = O + (size_t)(b * S_ + q_base + 16 * ni + c) * D_ + h * 64;
#pragma unroll
        for (int mi = 0; mi < 4; ++mi) {
            uint2 uo;
            uo.x = (u32)f2bf(acc_o[mi][ni][0] * inv_l) |
                   ((u32)f2bf(acc_o[mi][ni][1] * inv_l) << 16);
            uo.y = (u32)f2bf(acc_o[mi][ni][2] * inv_l) |
                   ((u32)f2bf(acc_o[mi][ni][3] * inv_l) << 16);
            *(uint2*)(op + 16 * mi + 4 * g) = uo;
        }
    }
}

// ---------------------------------------------------------------------------
extern "C" void kernel_launch(void* const* d_in, const int* in_sizes, int n_in,
                              void* d_out, int out_size, void* d_ws, size_t ws_size,
                              hipStream_t stream) {
    (void)in_sizes; (void)n_in; (void)out_size; (void)ws_size;
    char* ws = (char*)d_ws;
    const size_t MB = 1ull << 20;
    const size_t KB = 1024;
    u16* xn   = (u16*)(ws);                 // 16 MB
    u16* wqkv = (u16*)(ws + 16 * MB);       // 6 MB  [3072][1024]
    u16* won  = (u16*)(ws + 22 * MB);       // 2 MB
    u16* w1n  = (u16*)(ws + 24 * MB);       // 8 MB
    u16* w2n  = (u16*)(ws + 32 * MB);       // 8 MB
    u16* bqkv = (u16*)(ws + 40 * MB);       // 6 KB
    u16* bon  = (u16*)(ws + 40 * MB + 64 * KB);
    u16* b1n  = (u16*)(ws + 40 * MB + 128 * KB);
    u16* b2n  = (u16*)(ws + 40 * MB + 192 * KB);
    u16* g1n  = (u16*)(ws + 40 * MB + 256 * KB);
    u16* be1n = (u16*)(ws + 40 * MB + 320 * KB);
    u16* g2n  = (u16*)(ws + 40 * MB + 384 * KB);
    u16* be2n = (u16*)(ws + 40 * MB + 448 * KB);
    int* flag = (int*)(ws + 40 * MB + 512 * KB);
    u16* h1   = (u16*)(ws + 48 * MB);       // 16 MB: ln1 out; attn out
    u16* qkv  = (u16*)(ws + 64 * MB);       // 48 MB: fused QKV
    float* x2 = (float*)(ws + 64 * MB);     // 32 MB, overlays qkv (dead after attn)
    u16* h2   = (u16*)(ws + 96 * MB);       // 16 MB, overlays qkv tail
    u16* f1   = (u16*)(ws + 112 * MB);      // 64 MB -> total 176 MB

    const int M = B_ * S_;  // 8192

    sniff_kernel<<<1, 256, 0, stream>>>((const u16*)d_in[2], flag);
    auto nrm = [&](const void* in, u16* out, int n) {
        norm_kernel<<<(n + 255) / 256, 256, 0, stream>>>(in, out, n, flag);
    };
    nrm(d_in[0],  xn,  B_ * S_ * D_);
    nrm(d_in[2],  wqkv,               D_ * D_);   // wq
    nrm(d_in[4],  wqkv + D_ * D_,     D_ * D_);   // wk
    nrm(d_in[6],  wqkv + 2 * D_ * D_, D_ * D_);   // wv
    nrm(d_in[8],  won, D_ * D_);
    nrm(d_in[10], w1n, DFF_ * D_);
    nrm(d_in[12], w2n, D_ * DFF_);
    {
        SmallTbl tb;
        tb.src[0] = d_in[3];  tb.dst[0] = bqkv;        tb.n[0] = D_;    // bq
        tb.src[1] = d_in[5];  tb.dst[1] = bqkv + D_;   tb.n[1] = D_;    // bk
        tb.src[2] = d_in[7];  tb.dst[2] = bqkv + 2 * D_; tb.n[2] = D_;  // bv
        tb.src[3] = d_in[9];  tb.dst[3] = bon;         tb.n[3] = D_;
        tb.src[4] = d_in[11]; tb.dst[4] = b1n;         tb.n[4] = DFF_;
        tb.src[5] = d_in[13]; tb.dst[5] = b2n;         tb.n[5] = D_;
        tb.src[6] = d_in[14]; tb.dst[6] = g1n;         tb.n[6] = 1;
        tb.src[7] = d_in[15]; tb.dst[7] = be1n;        tb.n[7] = 1;
        tb.src[8] = d_in[16]; tb.dst[8] = g2n;         tb.n[8] = 1;
        tb.src[9] = d_in[17]; tb.dst[9] = be2n;        tb.n[9] = 1;
        const int tot = 5 * D_ + DFF_ + 4;
        norm_small<<<(tot + 255) / 256, 256, 0, stream>>>(tb, flag);
    }

    ln_kernel<0><<<M, 256, 0, stream>>>((const void*)xn, g1n, be1n, h1);
    gemm_bt<0, 0, 0><<<dim3(LDQKV / 128, M / 128), 256, 0, stream>>>(h1, wqkv, bqkv, nullptr, qkv, M, LDQKV, D_, nullptr);
    attn_mfma<<<dim3(S_ / 256, B_ * H_), 256, 0, stream>>>(qkv, h1);
    gemm_bt<0, 1, 1><<<dim3(D_ / 128, M / 128), 256, 0, stream>>>(h1, won, bon, (const void*)xn, x2, M, D_, D_, nullptr);
    ln_kernel<1><<<M, 256, 0, stream>>>((const void*)x2, g2n, be2n, h2);
    gemm_bt<1, 0, 0><<<dim3(DFF_ / 128, M / 128), 256, 0, stream>>>(h2, w1n, b1n, nullptr, f1, M, DFF_, D_, nullptr);
    gemm_bt<0, 2, 2><<<dim3(D_ / 128, M / 128), 256, 0, stream>>>(f1, w2n, b2n, (const void*)x2, (void*)d_out, M, D_, DFF_, flag);
}

// Round 5
// 566.719 us; speedup vs baseline: 2.5909x; 1.0386x over previous
//
#include <hip/hip_runtime.h>

typedef unsigned short u16;
typedef unsigned int u32;
typedef __attribute__((ext_vector_type(8))) __bf16 bf16x8;
typedef __attribute__((ext_vector_type(4))) float f32x4;

#define B_ 8
#define S_ 1024
#define D_ 1024
#define H_ 16
#define DK_ 64
#define DFF_ 4096
#define LDQKV 3072

__device__ __forceinline__ float bflo(u32 u) { return __uint_as_float(u << 16); }
__device__ __forceinline__ float bfhi(u32 u) { return __uint_as_float(u & 0xffff0000u); }
__device__ __forceinline__ u16 f2bf(float f) {
    u32 u = __float_as_uint(f);
    u += 0x7fffu + ((u >> 16) & 1u);   // RNE
    return (u16)(u >> 16);
}

// async global->LDS DMA, 16B per lane; LDS dest = wave-uniform base + lane*16
__device__ __forceinline__ void gl2lds16(const u16* g, u16* l) {
    __builtin_amdgcn_global_load_lds(
        (const __attribute__((address_space(1))) void*)g,
        (__attribute__((address_space(3))) void*)l, 16, 0, 0);
}

// ---------------------------------------------------------------------------
// Dtype sniffer (validated round 2: inputs are fp32). Kept for safety.
// ---------------------------------------------------------------------------
__global__ __launch_bounds__(256) void sniff_kernel(const u16* __restrict__ w,
                                                    int* __restrict__ flag) {
    float mx = 0.f;
    for (int i = threadIdx.x; i < 4096; i += 256) {
        float v = fabsf(bflo((u32)w[i]));
        if (!isnan(v)) mx = fmaxf(mx, v);
    }
#pragma unroll
    for (int m = 1; m < 64; m <<= 1) mx = fmaxf(mx, __shfl_xor(mx, m, 64));
    __shared__ float wmx[4];
    if ((threadIdx.x & 63) == 0) wmx[threadIdx.x >> 6] = mx;
    __syncthreads();
    if (threadIdx.x == 0) {
        float m2 = fmaxf(fmaxf(wmx[0], wmx[1]), fmaxf(wmx[2], wmx[3]));
        *flag = (m2 > 1e3f) ? 1 : 0;
    }
}

__global__ __launch_bounds__(256) void norm_kernel(const void* __restrict__ in,
                                                   u16* __restrict__ out, int n,
                                                   const int* __restrict__ flag) {
    const int i = blockIdx.x * 256 + threadIdx.x;
    if (i >= n) return;
    if (*flag)
        out[i] = f2bf(((const float*)in)[i]);
    else
        out[i] = ((const u16*)in)[i];
}

// fused conversion of the 10 small tensors (biases + scalars) in one dispatch
struct SmallTbl {
    const void* src[10];
    u16* dst[10];
    int n[10];
};
__global__ __launch_bounds__(256) void norm_small(SmallTbl tb,
                                                  const int* __restrict__ flag) {
    int i = blockIdx.x * 256 + threadIdx.x;
    const int f = *flag;
#pragma unroll
    for (int j = 0; j < 10; ++j) {
        if (i < tb.n[j]) {
            if (f)
                tb.dst[j][i] = f2bf(((const float*)tb.src[j])[i]);
            else
                tb.dst[j][i] = ((const u16*)tb.src[j])[i];
            return;
        }
        i -= tb.n[j];
    }
}

// ---------------------------------------------------------------------------
// LayerNorm (ddof=1, scalar gamma/beta). One block per row of 1024.
// INF: 0 = bf16 input, 1 = fp32 input, 2 = runtime (fp32 if *flag).
// ---------------------------------------------------------------------------
template <int INF>
__global__ __launch_bounds__(256) void ln_kernel(const void* __restrict__ in,
                                                 const u16* __restrict__ gs,
                                                 const u16* __restrict__ bs,
                                                 u16* __restrict__ out,
                                                 const int* __restrict__ flag) {
    const int row = blockIdx.x, t = threadIdx.x;
    const bool f32in = (INF == 1) || (INF == 2 && flag[0] != 0);
    float v0, v1, v2, v3;
    if (f32in) {
        const float* p = (const float*)in + (size_t)row * D_ + t * 4;
        float4 f = *(const float4*)p;
        v0 = f.x; v1 = f.y; v2 = f.z; v3 = f.w;
    } else {
        const u16* p = (const u16*)in + (size_t)row * D_ + t * 4;
        uint2 u = *(const uint2*)p;
        v0 = bflo(u.x); v1 = bfhi(u.x); v2 = bflo(u.y); v3 = bfhi(u.y);
    }
    float s = v0 + v1 + v2 + v3;
    float sq = v0 * v0 + v1 * v1 + v2 * v2 + v3 * v3;
#pragma unroll
    for (int m = 1; m < 64; m <<= 1) {
        s += __shfl_xor(s, m, 64);
        sq += __shfl_xor(sq, m, 64);
    }
    __shared__ float ss[4], sqs[4];
    const int w = t >> 6;
    if ((t & 63) == 0) { ss[w] = s; sqs[w] = sq; }
    __syncthreads();
    s = ss[0] + ss[1] + ss[2] + ss[3];
    sq = sqs[0] + sqs[1] + sqs[2] + sqs[3];
    const float mu = s * (1.f / 1024.f);
    float var = (sq - 1024.f * mu * mu) * (1.f / 1023.f);
    var = fmaxf(var, 0.f);
    const float rstd = rsqrtf(var + 1e-5f);
    const float gm = bflo((u32)gs[0]);
    const float bt = bflo((u32)bs[0]);
    const float y0 = gm * (v0 - mu) * rstd + bt;
    const float y1 = gm * (v1 - mu) * rstd + bt;
    const float y2 = gm * (v2 - mu) * rstd + bt;
    const float y3 = gm * (v3 - mu) * rstd + bt;
    uint2 uo;
    uo.x = (u32)f2bf(y0) | ((u32)f2bf(y1) << 16);
    uo.y = (u32)f2bf(y2) | ((u32)f2bf(y3) << 16);
    *(uint2*)(out + (size_t)row * D_ + t * 4) = uo;
}

// ---------------------------------------------------------------------------
// GEMM, m97 structure + two fixes for the round-4 counters:
//  (a) grouped grid swizzle: 1D grid, groups of 8 m-tiles x all n-tiles,
//      m-fastest within group -> ids===x (mod 8) [one XCD] keep a fixed
//      128-row A-slab in their L2 while W streams through L3 in lockstep.
//  (b) XOR-swizzled LDS k-chunk layout: global chunk kc of row r lives at
//      slot kc^(r&3)^((r>>2)&3). DMA lanes fetch the permuted chunk (same
//      64B segment -> coalescing intact); frag reads spread 16 lanes over
//      8 banks = 2-way (free) instead of 8-way on banks {0,16}.
// RES: 0 none, 2 fp32 residual, 3 runtime-dtype residual (flag).
// OUTF: 0 bf16 out, 1 fp32 out, 2 runtime (fp32 if *oflag else bf16).
// ---------------------------------------------------------------------------
template <int RELU, int RES, int OUTF>
__global__ __launch_bounds__(256, 2) void gemm_bt(const u16* __restrict__ A,
                                                  const u16* __restrict__ W,
                                                  const u16* __restrict__ bias,
                                                  const void* __restrict__ res,
                                                  void* __restrict__ out,
                                                  int M, int N, int K,
                                                  const int* __restrict__ oflag) {
    __shared__ __align__(16) u16 As[128 * 32];
    __shared__ __align__(16) u16 Bs[128 * 32];
    const int t = threadIdx.x;
    const int lane = t & 63, w = t >> 6;
    const int wm = w >> 1, wn = w & 1;

    // grouped swizzle (ny = M/128 divisible by 8 for all our shapes)
    const int nx = N >> 7;
    const int gsz = nx << 3;
    const int id = blockIdx.x;
    const int grp = id / gsz;
    const int rem = id - grp * gsz;
    const int m0 = ((grp << 3) + (rem & 7)) << 7;
    const int n0 = (rem >> 3) << 7;

    f32x4 acc[4][4];
#pragma unroll
    for (int mi = 0; mi < 4; ++mi)
#pragma unroll
        for (int ni = 0; ni < 4; ++ni) acc[mi][ni] = (f32x4){0.f, 0.f, 0.f, 0.f};

    // staging: lane l = (row sr, slot sk); slot sk holds global chunk swz(sr,sk)
    const int sr = lane >> 2, sk = lane & 3;
    const int skg = sk ^ (sr & 3) ^ ((sr >> 2) & 3);
    const u16* Ag0 = A + (size_t)(m0 + w * 16 + sr) * K + skg * 8;
    const u16* Bg0 = W + (size_t)(n0 + w * 16 + sr) * K + skg * 8;
    const size_t h64 = (size_t)64 * K;
    u16* Asd0 = &As[(w * 16) * 32];
    u16* Asd1 = &As[(64 + w * 16) * 32];
    u16* Bsd0 = &Bs[(w * 16) * 32];
    u16* Bsd1 = &Bs[(64 + w * 16) * 32];

    // read side: row wm*64+mi*16+c, want chunk g -> slot g^(c&3)^((c>>2)&3)
    const int c = lane & 15, g = lane >> 4;
    const int swc = g ^ (c & 3) ^ ((c >> 2) & 3);
    const u16* As_r = &As[(wm * 64 + c) * 32 + swc * 8];
    const u16* Bs_r = &Bs[(wn * 64 + c) * 32 + swc * 8];

    for (int kt = 0; kt < K; kt += 32) {
        __syncthreads();  // all waves done reading prev tile
        gl2lds16(Ag0 + kt, Asd0);
        gl2lds16(Ag0 + h64 + kt, Asd1);
        gl2lds16(Bg0 + kt, Bsd0);
        gl2lds16(Bg0 + h64 + kt, Bsd1);
        __syncthreads();  // drains vmcnt -> DMA'd data visible
        bf16x8 af[4], bfr[4];
#pragma unroll
        for (int i = 0; i < 4; ++i) {
            af[i] = *(const bf16x8*)(As_r + i * 16 * 32);
            bfr[i] = *(const bf16x8*)(Bs_r + i * 16 * 32);
        }
#pragma unroll
        for (int mi = 0; mi < 4; ++mi)
#pragma unroll
            for (int ni = 0; ni < 4; ++ni)
                acc[mi][ni] = __builtin_amdgcn_mfma_f32_16x16x32_bf16(af[mi], bfr[ni], acc[mi][ni], 0, 0, 0);
    }

    const int fl = oflag ? oflag[0] : 0;
    const bool f32o = (OUTF == 1) || (OUTF == 2 && fl != 0);
    const int qd = lane >> 4, cl = lane & 15;
#pragma unroll
    for (int ni = 0; ni < 4; ++ni) {
        const int col = n0 + wn * 64 + ni * 16 + cl;
        const float bv = bflo((u32)bias[col]);
#pragma unroll
        for (int mi = 0; mi < 4; ++mi) {
#pragma unroll
            for (int j = 0; j < 4; ++j) {
                const int row = m0 + wm * 64 + mi * 16 + qd * 4 + j;
                float vv = acc[mi][ni][j] + bv;
                if (RELU) vv = fmaxf(vv, 0.f);
                if (RES == 2) vv += ((const float*)res)[(size_t)row * N + col];
                if (RES == 3) {
                    if (fl)
                        vv += ((const float*)res)[(size_t)row * N + col];
                    else
                        vv += bflo((u32)((const u16*)res)[(size_t)row * N + col]);
                }
                if (f32o)
                    ((float*)out)[(size_t)row * N + col] = vv;
                else
                    ((u16*)out)[(size_t)row * N + col] = f2bf(vv);
            }
        }
    }
}

// ---------------------------------------------------------------------------
// MFMA flash attention over the fused QKV buffer (row stride LDQKV=3072;
// Q at +0, K at +1024, V at +2048). Structure validated rounds 3-4.
// ---------------------------------------------------------------------------
__global__ __launch_bounds__(256, 2) void attn_mfma(const u16* __restrict__ QKV,
                                                    u16* __restrict__ O) {
    __shared__ __align__(16) u16 lds[6 * 64 * 72];  // Ks | VsT | P x4 waves
    u16* Ks = lds;
    u16* VsT = lds + 64 * 72;

    const int t = threadIdx.x;
    const int lane = t & 63, w = t >> 6;
    u16* Pw = lds + (2 + w) * 64 * 72;
    const int b = blockIdx.y >> 4, h = blockIdx.y & 15;
    const int q_base = blockIdx.x * 256 + w * 64;
    const int c = lane & 15, g = lane >> 4;
    const float SC = 0.18033688011112042f;  // (1/8)*log2(e)

    bf16x8 qfrag[4][2];
#pragma unroll
    for (int ni = 0; ni < 4; ++ni)
#pragma unroll
        for (int kc = 0; kc < 2; ++kc)
            qfrag[ni][kc] = *(const bf16x8*)(QKV + (size_t)(b * S_ + q_base + 16 * ni + c) * LDQKV +
                                             h * 64 + kc * 32 + 8 * g);

    f32x4 acc_o[4][4];
#pragma unroll
    for (int mi = 0; mi < 4; ++mi)
#pragma unroll
        for (int ni = 0; ni < 4; ++ni) acc_o[mi][ni] = (f32x4){0.f, 0.f, 0.f, 0.f};
    float m_st[4] = {-1e30f, -1e30f, -1e30f, -1e30f};
    float l_st[4] = {0.f, 0.f, 0.f, 0.f};

    const size_t kbase = (size_t)(b * S_) * LDQKV + 1024 + h * 64;
    const size_t vbase = (size_t)(b * S_) * LDQKV + 2048 + h * 64;
    const int srow = t >> 2, sc4 = t & 3;

    for (int kt = 0; kt < 16; ++kt) {
        __syncthreads();
        {
            const u16* kp = QKV + kbase + (size_t)(kt * 64 + srow) * LDQKV + sc4 * 16;
            uint4 k0 = *(const uint4*)kp;
            uint4 k1 = *(const uint4*)(kp + 8);
            *(uint4*)&Ks[srow * 72 + sc4 * 16] = k0;
            *(uint4*)&Ks[srow * 72 + sc4 * 16 + 8] = k1;
            const u16* vp = QKV + vbase + (size_t)(kt * 64 + srow) * LDQKV + sc4 * 16;
            uint4 v0 = *(const uint4*)vp;
            uint4 v1 = *(const uint4*)(vp + 8);
            u32 vw[8] = {v0.x, v0.y, v0.z, v0.w, v1.x, v1.y, v1.z, v1.w};
#pragma unroll
            for (int i = 0; i < 8; ++i) {
                VsT[(sc4 * 16 + 2 * i) * 72 + srow] = (u16)(vw[i] & 0xffffu);
                VsT[(sc4 * 16 + 2 * i + 1) * 72 + srow] = (u16)(vw[i] >> 16);
            }
        }
        __syncthreads();

        f32x4 acc_s[4][4];
#pragma unroll
        for (int mi = 0; mi < 4; ++mi)
#pragma unroll
            for (int ni = 0; ni < 4; ++ni) acc_s[mi][ni] = (f32x4){0.f, 0.f, 0.f, 0.f};
#pragma unroll
        for (int kc = 0; kc < 2; ++kc) {
            bf16x8 kf[4];
#pragma unroll
            for (int mi = 0; mi < 4; ++mi)
                kf[mi] = *(const bf16x8*)&Ks[(16 * mi + c) * 72 + kc * 32 + 8 * g];
#pragma unroll
            for (int mi = 0; mi < 4; ++mi)
#pragma unroll
                for (int ni = 0; ni < 4; ++ni)
                    acc_s[mi][ni] = __builtin_amdgcn_mfma_f32_16x16x32_bf16(
                        kf[mi], qfrag[ni][kc], acc_s[mi][ni], 0, 0, 0);
        }

        float alpha[4];
#pragma unroll
        for (int ni = 0; ni < 4; ++ni) {
            float mx = -1e30f;
#pragma unroll
            for (int mi = 0; mi < 4; ++mi) {
#pragma unroll
                for (int j = 0; j < 4; ++j) {
                    acc_s[mi][ni][j] *= SC;
                    mx = fmaxf(mx, acc_s[mi][ni][j]);
                }
            }
            mx = fmaxf(mx, __shfl_xor(mx, 16, 64));
            mx = fmaxf(mx, __shfl_xor(mx, 32, 64));
            const float mn = fmaxf(m_st[ni], mx);
            alpha[ni] = exp2f(m_st[ni] - mn);
            m_st[ni] = mn;
            float sum = 0.f;
#pragma unroll
            for (int mi = 0; mi < 4; ++mi) {
                float p0 = exp2f(acc_s[mi][ni][0] - mn);
                float p1 = exp2f(acc_s[mi][ni][1] - mn);
                float p2 = exp2f(acc_s[mi][ni][2] - mn);
                float p3 = exp2f(acc_s[mi][ni][3] - mn);
                sum += (p0 + p1) + (p2 + p3);
                uint2 pk;
                pk.x = (u32)f2bf(p0) | ((u32)f2bf(p1) << 16);
                pk.y = (u32)f2bf(p2) | ((u32)f2bf(p3) << 16);
                *(uint2*)&Pw[(16 * ni + c) * 72 + 16 * mi + 4 * g] = pk;
            }
            sum += __shfl_xor(sum, 16, 64);
            sum += __shfl_xor(sum, 32, 64);
            l_st[ni] = l_st[ni] * alpha[ni] + sum;
        }
#pragma unroll
        for (int mi = 0; mi < 4; ++mi)
#pragma unroll
            for (int ni = 0; ni < 4; ++ni) {
#pragma unroll
                for (int j = 0; j < 4; ++j) acc_o[mi][ni][j] *= alpha[ni];
            }

#pragma unroll
        for (int kc = 0; kc < 2; ++kc) {
            bf16x8 vf[4], pf[4];
#pragma unroll
            for (int mi = 0; mi < 4; ++mi)
                vf[mi] = *(const bf16x8*)&VsT[(16 * mi + c) * 72 + kc * 32 + 8 * g];
#pragma unroll
            for (int ni = 0; ni < 4; ++ni)
                pf[ni] = *(const bf16x8*)&Pw[(16 * ni + c) * 72 + kc * 32 + 8 * g];
#pragma unroll
            for (int mi = 0; mi < 4; ++mi)
#pragma unroll
                for (int ni = 0; ni < 4; ++ni)
                    acc_o[mi][ni] = __builtin_amdgcn_mfma_f32_16x16x32_bf16(
                        vf[mi], pf[ni], acc_o[mi][ni], 0, 0, 0);
        }
    }

#pragma unroll
    for (int ni = 0; ni < 4; ++ni) {
        const float inv_l = 1.f / l_st[ni];
        u16* op = O + (size_t)(b * S_ + q_base + 16 * ni + c) * D_ + h * 64;
#pragma unroll
        for (int mi = 0; mi < 4; ++mi) {
            uint2 uo;
            uo.x = (u32)f2bf(acc_o[mi][ni][0] * inv_l) |
                   ((u32)f2bf(acc_o[mi][ni][1] * inv_l) << 16);
            uo.y = (u32)f2bf(acc_o[mi][ni][2] * inv_l) |
                   ((u32)f2bf(acc_o[mi][ni][3] * inv_l) << 16);
            *(uint2*)(op + 16 * mi + 4 * g) = uo;
        }
    }
}

// ---------------------------------------------------------------------------
extern "C" void kernel_launch(void* const* d_in, const int* in_sizes, int n_in,
                              void* d_out, int out_size, void* d_ws, size_t ws_size,
                              hipStream_t stream) {
    (void)in_sizes; (void)n_in; (void)out_size; (void)ws_size;
    char* ws = (char*)d_ws;
    const size_t MB = 1ull << 20;
    const size_t KB = 1024;
    u16* wqkv = (u16*)(ws + 16 * MB);       // 6 MB  [3072][1024]
    u16* won  = (u16*)(ws + 22 * MB);       // 2 MB
    u16* w1n  = (u16*)(ws + 24 * MB);       // 8 MB
    u16* w2n  = (u16*)(ws + 32 * MB);       // 8 MB
    u16* bqkv = (u16*)(ws + 40 * MB);       // 6 KB
    u16* bon  = (u16*)(ws + 40 * MB + 64 * KB);
    u16* b1n  = (u16*)(ws + 40 * MB + 128 * KB);
    u16* b2n  = (u16*)(ws + 40 * MB + 192 * KB);
    u16* g1n  = (u16*)(ws + 40 * MB + 256 * KB);
    u16* be1n = (u16*)(ws + 40 * MB + 320 * KB);
    u16* g2n  = (u16*)(ws + 40 * MB + 384 * KB);
    u16* be2n = (u16*)(ws + 40 * MB + 448 * KB);
    int* flag = (int*)(ws + 40 * MB + 512 * KB);
    u16* h1   = (u16*)(ws + 48 * MB);       // 16 MB: ln1 out; attn out
    u16* qkv  = (u16*)(ws + 64 * MB);       // 48 MB: fused QKV
    float* x2 = (float*)(ws + 64 * MB);     // 32 MB, overlays qkv (dead after attn)
    u16* h2   = (u16*)(ws + 96 * MB);       // 16 MB, overlays qkv tail
    u16* f1   = (u16*)(ws + 112 * MB);      // 64 MB -> total 176 MB

    const int M = B_ * S_;  // 8192

    sniff_kernel<<<1, 256, 0, stream>>>((const u16*)d_in[2], flag);
    auto nrm = [&](const void* in, u16* out, int n) {
        norm_kernel<<<(n + 255) / 256, 256, 0, stream>>>(in, out, n, flag);
    };
    nrm(d_in[2],  wqkv,               D_ * D_);   // wq
    nrm(d_in[4],  wqkv + D_ * D_,     D_ * D_);   // wk
    nrm(d_in[6],  wqkv + 2 * D_ * D_, D_ * D_);   // wv
    nrm(d_in[8],  won, D_ * D_);
    nrm(d_in[10], w1n, DFF_ * D_);
    nrm(d_in[12], w2n, D_ * DFF_);
    {
        SmallTbl tb;
        tb.src[0] = d_in[3];  tb.dst[0] = bqkv;          tb.n[0] = D_;   // bq
        tb.src[1] = d_in[5];  tb.dst[1] = bqkv + D_;     tb.n[1] = D_;   // bk
        tb.src[2] = d_in[7];  tb.dst[2] = bqkv + 2 * D_; tb.n[2] = D_;   // bv
        tb.src[3] = d_in[9];  tb.dst[3] = bon;           tb.n[3] = D_;
        tb.src[4] = d_in[11]; tb.dst[4] = b1n;           tb.n[4] = DFF_;
        tb.src[5] = d_in[13]; tb.dst[5] = b2n;           tb.n[5] = D_;
        tb.src[6] = d_in[14]; tb.dst[6] = g1n;           tb.n[6] = 1;
        tb.src[7] = d_in[15]; tb.dst[7] = be1n;          tb.n[7] = 1;
        tb.src[8] = d_in[16]; tb.dst[8] = g2n;           tb.n[8] = 1;
        tb.src[9] = d_in[17]; tb.dst[9] = be2n;          tb.n[9] = 1;
        const int tot = 5 * D_ + DFF_ + 4;
        norm_small<<<(tot + 255) / 256, 256, 0, stream>>>(tb, flag);
    }

    // ln1 reads x directly with runtime dtype (no bf16 copy of x needed)
    ln_kernel<2><<<M, 256, 0, stream>>>(d_in[0], g1n, be1n, h1, flag);
    gemm_bt<0, 0, 0><<<(LDQKV / 128) * (M / 128), 256, 0, stream>>>(h1, wqkv, bqkv, nullptr, qkv, M, LDQKV, D_, flag);
    attn_mfma<<<dim3(S_ / 256, B_ * H_), 256, 0, stream>>>(qkv, h1);
    // O-proj: residual = original x (runtime dtype), fp32 out
    gemm_bt<0, 3, 1><<<(D_ / 128) * (M / 128), 256, 0, stream>>>(h1, won, bon, d_in[0], x2, M, D_, D_, flag);
    ln_kernel<1><<<M, 256, 0, stream>>>((const void*)x2, g2n, be2n, h2, flag);
    gemm_bt<1, 0, 0><<<(DFF_ / 128) * (M / 128), 256, 0, stream>>>(h2, w1n, b1n, nullptr, f1, M, DFF_, D_, flag);
    gemm_bt<0, 2, 2><<<(D_ / 128) * (M / 128), 256, 0, stream>>>(f1, w2n, b2n, (const void*)x2, (void*)d_out, M, D_, DFF_, flag);
}

// Round 6
// 534.880 us; speedup vs baseline: 2.7451x; 1.0595x over previous
//
#include <hip/hip_runtime.h>

typedef unsigned short u16;
typedef unsigned int u32;
typedef __attribute__((ext_vector_type(8))) __bf16 bf16x8;
typedef __attribute__((ext_vector_type(4))) float f32x4;

#define B_ 8
#define S_ 1024
#define D_ 1024
#define H_ 16
#define DK_ 64
#define DFF_ 4096
#define LDQKV 3072

__device__ __forceinline__ float bflo(u32 u) { return __uint_as_float(u << 16); }
__device__ __forceinline__ float bfhi(u32 u) { return __uint_as_float(u & 0xffff0000u); }
__device__ __forceinline__ u16 f2bf(float f) {
    u32 u = __float_as_uint(f);
    u += 0x7fffu + ((u >> 16) & 1u);   // RNE
    return (u16)(u >> 16);
}

// async global->LDS DMA, 16B per lane; LDS dest = wave-uniform base + lane*16
__device__ __forceinline__ void gl2lds16(const u16* g, u16* l) {
    __builtin_amdgcn_global_load_lds(
        (const __attribute__((address_space(1))) void*)g,
        (__attribute__((address_space(3))) void*)l, 16, 0, 0);
}

// ---------------------------------------------------------------------------
// Dtype sniffer (validated round 2: inputs are fp32). Kept for safety.
// ---------------------------------------------------------------------------
__global__ __launch_bounds__(256) void sniff_kernel(const u16* __restrict__ w,
                                                    int* __restrict__ flag) {
    float mx = 0.f;
    for (int i = threadIdx.x; i < 4096; i += 256) {
        float v = fabsf(bflo((u32)w[i]));
        if (!isnan(v)) mx = fmaxf(mx, v);
    }
#pragma unroll
    for (int m = 1; m < 64; m <<= 1) mx = fmaxf(mx, __shfl_xor(mx, m, 64));
    __shared__ float wmx[4];
    if ((threadIdx.x & 63) == 0) wmx[threadIdx.x >> 6] = mx;
    __syncthreads();
    if (threadIdx.x == 0) {
        float m2 = fmaxf(fmaxf(wmx[0], wmx[1]), fmaxf(wmx[2], wmx[3]));
        *flag = (m2 > 1e3f) ? 1 : 0;
    }
}

__global__ __launch_bounds__(256) void norm_kernel(const void* __restrict__ in,
                                                   u16* __restrict__ out, int n,
                                                   const int* __restrict__ flag) {
    const int i = blockIdx.x * 256 + threadIdx.x;
    if (i >= n) return;
    if (*flag)
        out[i] = f2bf(((const float*)in)[i]);
    else
        out[i] = ((const u16*)in)[i];
}

// fused conversion of the 10 small tensors (biases + scalars) in one dispatch
struct SmallTbl {
    const void* src[10];
    u16* dst[10];
    int n[10];
};
__global__ __launch_bounds__(256) void norm_small(SmallTbl tb,
                                                  const int* __restrict__ flag) {
    int i = blockIdx.x * 256 + threadIdx.x;
    const int f = *flag;
#pragma unroll
    for (int j = 0; j < 10; ++j) {
        if (i < tb.n[j]) {
            if (f)
                tb.dst[j][i] = f2bf(((const float*)tb.src[j])[i]);
            else
                tb.dst[j][i] = ((const u16*)tb.src[j])[i];
            return;
        }
        i -= tb.n[j];
    }
}

// ---------------------------------------------------------------------------
// LayerNorm (ddof=1, scalar gamma/beta). One block per row of 1024.
// INF: 0 = bf16 input, 1 = fp32 input, 2 = runtime (fp32 if *flag).
// ---------------------------------------------------------------------------
template <int INF>
__global__ __launch_bounds__(256) void ln_kernel(const void* __restrict__ in,
                                                 const u16* __restrict__ gs,
                                                 const u16* __restrict__ bs,
                                                 u16* __restrict__ out,
                                                 const int* __restrict__ flag) {
    const int row = blockIdx.x, t = threadIdx.x;
    const bool f32in = (INF == 1) || (INF == 2 && flag[0] != 0);
    float v0, v1, v2, v3;
    if (f32in) {
        const float* p = (const float*)in + (size_t)row * D_ + t * 4;
        float4 f = *(const float4*)p;
        v0 = f.x; v1 = f.y; v2 = f.z; v3 = f.w;
    } else {
        const u16* p = (const u16*)in + (size_t)row * D_ + t * 4;
        uint2 u = *(const uint2*)p;
        v0 = bflo(u.x); v1 = bfhi(u.x); v2 = bflo(u.y); v3 = bfhi(u.y);
    }
    float s = v0 + v1 + v2 + v3;
    float sq = v0 * v0 + v1 * v1 + v2 * v2 + v3 * v3;
#pragma unroll
    for (int m = 1; m < 64; m <<= 1) {
        s += __shfl_xor(s, m, 64);
        sq += __shfl_xor(sq, m, 64);
    }
    __shared__ float ss[4], sqs[4];
    const int w = t >> 6;
    if ((t & 63) == 0) { ss[w] = s; sqs[w] = sq; }
    __syncthreads();
    s = ss[0] + ss[1] + ss[2] + ss[3];
    sq = sqs[0] + sqs[1] + sqs[2] + sqs[3];
    const float mu = s * (1.f / 1024.f);
    float var = (sq - 1024.f * mu * mu) * (1.f / 1023.f);
    var = fmaxf(var, 0.f);
    const float rstd = rsqrtf(var + 1e-5f);
    const float gm = bflo((u32)gs[0]);
    const float bt = bflo((u32)bs[0]);
    const float y0 = gm * (v0 - mu) * rstd + bt;
    const float y1 = gm * (v1 - mu) * rstd + bt;
    const float y2 = gm * (v2 - mu) * rstd + bt;
    const float y3 = gm * (v3 - mu) * rstd + bt;
    uint2 uo;
    uo.x = (u32)f2bf(y0) | ((u32)f2bf(y1) << 16);
    uo.y = (u32)f2bf(y2) | ((u32)f2bf(y3) << 16);
    *(uint2*)(out + (size_t)row * D_ + t * 4) = uo;
}

// ---------------------------------------------------------------------------
// GEMM, round 6: BK=64 (half the barrier/drain count vs BK=32) +
// __launch_bounds__(256,4) (target 4 blocks/CU; VGPR+AGPR must fit 128/wave).
//  - grid swizzle (validated r5: FETCH 303->84 MB): groups of 8 m-tiles,
//    m-fastest -> ids===x (mod 8) share one A-slab per XCD-L2.
//  - LDS tiles 128x64 (32 KB total), XOR chunk swizzle: 16B-chunk j of row r
//    stored at slot j^(r&7). Frag reads: 16 lanes -> 8 start banks, 2 lanes
//    per bank at identical bank-word phase (2-way = free, m136). The
//    residual 4 cyc/b128 (r4/r5 counter, = m134's 12-cyc b128) is structural.
// RES: 0 none, 2 fp32 residual, 3 runtime-dtype residual (flag).
// OUTF: 0 bf16 out, 1 fp32 out, 2 runtime (fp32 if *oflag else bf16).
// ---------------------------------------------------------------------------
template <int RELU, int RES, int OUTF>
__global__ __launch_bounds__(256, 4) void gemm_bt(const u16* __restrict__ A,
                                                  const u16* __restrict__ W,
                                                  const u16* __restrict__ bias,
                                                  const void* __restrict__ res,
                                                  void* __restrict__ out,
                                                  int M, int N, int K,
                                                  const int* __restrict__ oflag) {
    __shared__ __align__(16) u16 As[128 * 64];
    __shared__ __align__(16) u16 Bs[128 * 64];
    const int t = threadIdx.x;
    const int lane = t & 63, w = t >> 6;
    const int wm = w >> 1, wn = w & 1;

    // grouped swizzle (ny = M/128 = 64, divisible by 8)
    const int nx = N >> 7;
    const int gsz = nx << 3;
    const int id = blockIdx.x;
    const int grp = id / gsz;
    const int rem = id - grp * gsz;
    const int m0 = ((grp << 3) + (rem & 7)) << 7;
    const int n0 = (rem >> 3) << 7;

    f32x4 acc[4][4];
#pragma unroll
    for (int mi = 0; mi < 4; ++mi)
#pragma unroll
        for (int ni = 0; ni < 4; ++ni) acc[mi][ni] = (f32x4){0.f, 0.f, 0.f, 0.f};

    // staging (BK=64): one inst = 8 rows x 128B. Wave w, inst i covers rows
    // i*32 + w*8 + (lane>>3); lane fetches global chunk (lane&7)^(row&7).
    const int r8 = lane >> 3, s8 = lane & 7;
    const int cg = s8 ^ r8;
    const u16* Ag = A + (size_t)(m0 + w * 8 + r8) * K + cg * 8;
    const u16* Bg = W + (size_t)(n0 + w * 8 + r8) * K + cg * 8;
    const size_t rI = (size_t)32 * K;  // 32-row stride between insts
    u16* Asd = &As[(w * 8) * 64];
    u16* Bsd = &Bs[(w * 8) * 64];

    // frag read: row wm*64+16i+c, k-round kc chunk (kc*4+g) at slot ^(c&7)
    const int c = lane & 15, g = lane >> 4;
    const u16* As_r = &As[(wm * 64 + c) * 64];
    const u16* Bs_r = &Bs[(wn * 64 + c) * 64];
    const int sl0 = (g ^ (c & 7)) * 8;
    const int sl1 = ((4 + g) ^ (c & 7)) * 8;

    for (int kt = 0; kt < K; kt += 64) {
        __syncthreads();  // all waves done reading prev tile
        gl2lds16(Ag, Asd);
        gl2lds16(Ag + rI, Asd + 32 * 64);
        gl2lds16(Ag + 2 * rI, Asd + 64 * 64);
        gl2lds16(Ag + 3 * rI, Asd + 96 * 64);
        gl2lds16(Bg, Bsd);
        gl2lds16(Bg + rI, Bsd + 32 * 64);
        gl2lds16(Bg + 2 * rI, Bsd + 64 * 64);
        gl2lds16(Bg + 3 * rI, Bsd + 96 * 64);
        Ag += 64; Bg += 64;
        __syncthreads();  // drains vmcnt -> DMA'd data visible
#pragma unroll
        for (int kc = 0; kc < 2; ++kc) {
            const int sl = kc ? sl1 : sl0;
            bf16x8 af[4], bfr[4];
#pragma unroll
            for (int i = 0; i < 4; ++i) {
                af[i] = *(const bf16x8*)(As_r + i * 16 * 64 + sl);
                bfr[i] = *(const bf16x8*)(Bs_r + i * 16 * 64 + sl);
            }
#pragma unroll
            for (int mi = 0; mi < 4; ++mi)
#pragma unroll
                for (int ni = 0; ni < 4; ++ni)
                    acc[mi][ni] = __builtin_amdgcn_mfma_f32_16x16x32_bf16(af[mi], bfr[ni], acc[mi][ni], 0, 0, 0);
        }
    }

    const int fl = oflag ? oflag[0] : 0;
    const bool f32o = (OUTF == 1) || (OUTF == 2 && fl != 0);
    const int qd = lane >> 4, cl = lane & 15;
#pragma unroll
    for (int ni = 0; ni < 4; ++ni) {
        const int col = n0 + wn * 64 + ni * 16 + cl;
        const float bv = bflo((u32)bias[col]);
#pragma unroll
        for (int mi = 0; mi < 4; ++mi) {
#pragma unroll
            for (int j = 0; j < 4; ++j) {
                const int row = m0 + wm * 64 + mi * 16 + qd * 4 + j;
                float vv = acc[mi][ni][j] + bv;
                if (RELU) vv = fmaxf(vv, 0.f);
                if (RES == 2) vv += ((const float*)res)[(size_t)row * N + col];
                if (RES == 3) {
                    if (fl)
                        vv += ((const float*)res)[(size_t)row * N + col];
                    else
                        vv += bflo((u32)((const u16*)res)[(size_t)row * N + col]);
                }
                if (f32o)
                    ((float*)out)[(size_t)row * N + col] = vv;
                else
                    ((u16*)out)[(size_t)row * N + col] = f2bf(vv);
            }
        }
    }
}

// ---------------------------------------------------------------------------
// MFMA flash attention over the fused QKV buffer (row stride LDQKV=3072;
// Q at +0, K at +1024, V at +2048). Structure validated rounds 3-5.
// ---------------------------------------------------------------------------
__global__ __launch_bounds__(256, 2) void attn_mfma(const u16* __restrict__ QKV,
                                                    u16* __restrict__ O) {
    __shared__ __align__(16) u16 lds[6 * 64 * 72];  // Ks | VsT | P x4 waves
    u16* Ks = lds;
    u16* VsT = lds + 64 * 72;

    const int t = threadIdx.x;
    const int lane = t & 63, w = t >> 6;
    u16* Pw = lds + (2 + w) * 64 * 72;
    const int b = blockIdx.y >> 4, h = blockIdx.y & 15;
    const int q_base = blockIdx.x * 256 + w * 64;
    const int c = lane & 15, g = lane >> 4;
    const float SC = 0.18033688011112042f;  // (1/8)*log2(e)

    bf16x8 qfrag[4][2];
#pragma unroll
    for (int ni = 0; ni < 4; ++ni)
#pragma unroll
        for (int kc = 0; kc < 2; ++kc)
            qfrag[ni][kc] = *(const bf16x8*)(QKV + (size_t)(b * S_ + q_base + 16 * ni + c) * LDQKV +
                                             h * 64 + kc * 32 + 8 * g);

    f32x4 acc_o[4][4];
#pragma unroll
    for (int mi = 0; mi < 4; ++mi)
#pragma unroll
        for (int ni = 0; ni < 4; ++ni) acc_o[mi][ni] = (f32x4){0.f, 0.f, 0.f, 0.f};
    float m_st[4] = {-1e30f, -1e30f, -1e30f, -1e30f};
    float l_st[4] = {0.f, 0.f, 0.f, 0.f};

    const size_t kbase = (size_t)(b * S_) * LDQKV + 1024 + h * 64;
    const size_t vbase = (size_t)(b * S_) * LDQKV + 2048 + h * 64;
    const int srow = t >> 2, sc4 = t & 3;

    for (int kt = 0; kt < 16; ++kt) {
        __syncthreads();
        {
            const u16* kp = QKV + kbase + (size_t)(kt * 64 + srow) * LDQKV + sc4 * 16;
            uint4 k0 = *(const uint4*)kp;
            uint4 k1 = *(const uint4*)(kp + 8);
            *(uint4*)&Ks[srow * 72 + sc4 * 16] = k0;
            *(uint4*)&Ks[srow * 72 + sc4 * 16 + 8] = k1;
            const u16* vp = QKV + vbase + (size_t)(kt * 64 + srow) * LDQKV + sc4 * 16;
            uint4 v0 = *(const uint4*)vp;
            uint4 v1 = *(const uint4*)(vp + 8);
            u32 vw[8] = {v0.x, v0.y, v0.z, v0.w, v1.x, v1.y, v1.z, v1.w};
#pragma unroll
            for (int i = 0; i < 8; ++i) {
                VsT[(sc4 * 16 + 2 * i) * 72 + srow] = (u16)(vw[i] & 0xffffu);
                VsT[(sc4 * 16 + 2 * i + 1) * 72 + srow] = (u16)(vw[i] >> 16);
            }
        }
        __syncthreads();

        f32x4 acc_s[4][4];
#pragma unroll
        for (int mi = 0; mi < 4; ++mi)
#pragma unroll
            for (int ni = 0; ni < 4; ++ni) acc_s[mi][ni] = (f32x4){0.f, 0.f, 0.f, 0.f};
#pragma unroll
        for (int kc = 0; kc < 2; ++kc) {
            bf16x8 kf[4];
#pragma unroll
            for (int mi = 0; mi < 4; ++mi)
                kf[mi] = *(const bf16x8*)&Ks[(16 * mi + c) * 72 + kc * 32 + 8 * g];
#pragma unroll
            for (int mi = 0; mi < 4; ++mi)
#pragma unroll
                for (int ni = 0; ni < 4; ++ni)
                    acc_s[mi][ni] = __builtin_amdgcn_mfma_f32_16x16x32_bf16(
                        kf[mi], qfrag[ni][kc], acc_s[mi][ni], 0, 0, 0);
        }

        float alpha[4];
#pragma unroll
        for (int ni = 0; ni < 4; ++ni) {
            float mx = -1e30f;
#pragma unroll
            for (int mi = 0; mi < 4; ++mi) {
#pragma unroll
                for (int j = 0; j < 4; ++j) {
                    acc_s[mi][ni][j] *= SC;
                    mx = fmaxf(mx, acc_s[mi][ni][j]);
                }
            }
            mx = fmaxf(mx, __shfl_xor(mx, 16, 64));
            mx = fmaxf(mx, __shfl_xor(mx, 32, 64));
            const float mn = fmaxf(m_st[ni], mx);
            alpha[ni] = exp2f(m_st[ni] - mn);
            m_st[ni] = mn;
            float sum = 0.f;
#pragma unroll
            for (int mi = 0; mi < 4; ++mi) {
                float p0 = exp2f(acc_s[mi][ni][0] - mn);
                float p1 = exp2f(acc_s[mi][ni][1] - mn);
                float p2 = exp2f(acc_s[mi][ni][2] - mn);
                float p3 = exp2f(acc_s[mi][ni][3] - mn);
                sum += (p0 + p1) + (p2 + p3);
                uint2 pk;
                pk.x = (u32)f2bf(p0) | ((u32)f2bf(p1) << 16);
                pk.y = (u32)f2bf(p2) | ((u32)f2bf(p3) << 16);
                *(uint2*)&Pw[(16 * ni + c) * 72 + 16 * mi + 4 * g] = pk;
            }
            sum += __shfl_xor(sum, 16, 64);
            sum += __shfl_xor(sum, 32, 64);
            l_st[ni] = l_st[ni] * alpha[ni] + sum;
        }
#pragma unroll
        for (int mi = 0; mi < 4; ++mi)
#pragma unroll
            for (int ni = 0; ni < 4; ++ni) {
#pragma unroll
                for (int j = 0; j < 4; ++j) acc_o[mi][ni][j] *= alpha[ni];
            }

#pragma unroll
        for (int kc = 0; kc < 2; ++kc) {
            bf16x8 vf[4], pf[4];
#pragma unroll
            for (int mi = 0; mi < 4; ++mi)
                vf[mi] = *(const bf16x8*)&VsT[(16 * mi + c) * 72 + kc * 32 + 8 * g];
#pragma unroll
            for (int ni = 0; ni < 4; ++ni)
                pf[ni] = *(const bf16x8*)&Pw[(16 * ni + c) * 72 + kc * 32 + 8 * g];
#pragma unroll
            for (int mi = 0; mi < 4; ++mi)
#pragma unroll
                for (int ni = 0; ni < 4; ++ni)
                    acc_o[mi][ni] = __builtin_amdgcn_mfma_f32_16x16x32_bf16(
                        vf[mi], pf[ni], acc_o[mi][ni], 0, 0, 0);
        }
    }

#pragma unroll
    for (int ni = 0; ni < 4; ++ni) {
        const float inv_l = 1.f / l_st[ni];
        u16* op = O + (size_t)(b * S_ + q_base + 16 * ni + c) * D_ + h * 64;
#pragma unroll
        for (int mi = 0; mi < 4; ++mi) {
            uint2 uo;
            uo.x = (u32)f2bf(acc_o[mi][ni][0] * inv_l) |
                   ((u32)f2bf(acc_o[mi][ni][1] * inv_l) << 16);
            uo.y = (u32)f2bf(acc_o[mi][ni][2] * inv_l) |
                   ((u32)f2bf(acc_o[mi][ni][3] * inv_l) << 16);
            *(uint2*)(op + 16 * mi + 4 * g) = uo;
        }
    }
}

// ---------------------------------------------------------------------------
extern "C" void kernel_launch(void* const* d_in, const int* in_sizes, int n_in,
                              void* d_out, int out_size, void* d_ws, size_t ws_size,
                              hipStream_t stream) {
    (void)in_sizes; (void)n_in; (void)out_size; (void)ws_size;
    char* ws = (char*)d_ws;
    const size_t MB = 1ull << 20;
    const size_t KB = 1024;
    u16* wqkv = (u16*)(ws + 16 * MB);       // 6 MB  [3072][1024]
    u16* won  = (u16*)(ws + 22 * MB);       // 2 MB
    u16* w1n  = (u16*)(ws + 24 * MB);       // 8 MB
    u16* w2n  = (u16*)(ws + 32 * MB);       // 8 MB
    u16* bqkv = (u16*)(ws + 40 * MB);       // 6 KB
    u16* bon  = (u16*)(ws + 40 * MB + 64 * KB);
    u16* b1n  = (u16*)(ws + 40 * MB + 128 * KB);
    u16* b2n  = (u16*)(ws + 40 * MB + 192 * KB);
    u16* g1n  = (u16*)(ws + 40 * MB + 256 * KB);
    u16* be1n = (u16*)(ws + 40 * MB + 320 * KB);
    u16* g2n  = (u16*)(ws + 40 * MB + 384 * KB);
    u16* be2n = (u16*)(ws + 40 * MB + 448 * KB);
    int* flag = (int*)(ws + 40 * MB + 512 * KB);
    u16* h1   = (u16*)(ws + 48 * MB);       // 16 MB: ln1 out; attn out
    u16* qkv  = (u16*)(ws + 64 * MB);       // 48 MB: fused QKV
    float* x2 = (float*)(ws + 64 * MB);     // 32 MB, overlays qkv (dead after attn)
    u16* h2   = (u16*)(ws + 96 * MB);       // 16 MB, overlays qkv tail
    u16* f1   = (u16*)(ws + 112 * MB);      // 64 MB -> total 176 MB

    const int M = B_ * S_;  // 8192

    sniff_kernel<<<1, 256, 0, stream>>>((const u16*)d_in[2], flag);
    auto nrm = [&](const void* in, u16* out, int n) {
        norm_kernel<<<(n + 255) / 256, 256, 0, stream>>>(in, out, n, flag);
    };
    nrm(d_in[2],  wqkv,               D_ * D_);   // wq
    nrm(d_in[4],  wqkv + D_ * D_,     D_ * D_);   // wk
    nrm(d_in[6],  wqkv + 2 * D_ * D_, D_ * D_);   // wv
    nrm(d_in[8],  won, D_ * D_);
    nrm(d_in[10], w1n, DFF_ * D_);
    nrm(d_in[12], w2n, D_ * DFF_);
    {
        SmallTbl tb;
        tb.src[0] = d_in[3];  tb.dst[0] = bqkv;          tb.n[0] = D_;   // bq
        tb.src[1] = d_in[5];  tb.dst[1] = bqkv + D_;     tb.n[1] = D_;   // bk
        tb.src[2] = d_in[7];  tb.dst[2] = bqkv + 2 * D_; tb.n[2] = D_;   // bv
        tb.src[3] = d_in[9];  tb.dst[3] = bon;           tb.n[3] = D_;
        tb.src[4] = d_in[11]; tb.dst[4] = b1n;           tb.n[4] = DFF_;
        tb.src[5] = d_in[13]; tb.dst[5] = b2n;           tb.n[5] = D_;
        tb.src[6] = d_in[14]; tb.dst[6] = g1n;           tb.n[6] = 1;
        tb.src[7] = d_in[15]; tb.dst[7] = be1n;          tb.n[7] = 1;
        tb.src[8] = d_in[16]; tb.dst[8] = g2n;           tb.n[8] = 1;
        tb.src[9] = d_in[17]; tb.dst[9] = be2n;          tb.n[9] = 1;
        const int tot = 5 * D_ + DFF_ + 4;
        norm_small<<<(tot + 255) / 256, 256, 0, stream>>>(tb, flag);
    }

    // ln1 reads x directly with runtime dtype (no bf16 copy of x needed)
    ln_kernel<2><<<M, 256, 0, stream>>>(d_in[0], g1n, be1n, h1, flag);
    gemm_bt<0, 0, 0><<<(LDQKV / 128) * (M / 128), 256, 0, stream>>>(h1, wqkv, bqkv, nullptr, qkv, M, LDQKV, D_, flag);
    attn_mfma<<<dim3(S_ / 256, B_ * H_), 256, 0, stream>>>(qkv, h1);
    // O-proj: residual = original x (runtime dtype), fp32 out
    gemm_bt<0, 3, 1><<<(D_ / 128) * (M / 128), 256, 0, stream>>>(h1, won, bon, d_in[0], x2, M, D_, D_, flag);
    ln_kernel<1><<<M, 256, 0, stream>>>((const void*)x2, g2n, be2n, h2, flag);
    gemm_bt<1, 0, 0><<<(DFF_ / 128) * (M / 128), 256, 0, stream>>>(h2, w1n, b1n, nullptr, f1, M, DFF_, D_, flag);
    gemm_bt<0, 2, 2><<<(D_ / 128) * (M / 128), 256, 0, stream>>>(f1, w2n, b2n, (const void*)x2, (void*)d_out, M, D_, DFF_, flag);
}